// Round 18
// baseline (1605.307 us; speedup 1.0000x reference)
//
#include <hip/hip_runtime.h>

// Problem constants (fixed by reference setup)
#define NN     10000      // variable nodes
#define NF     80000      // factors
#define NE     160000     // directed edges per direction
#define SDIM   64         // state dim
#define HMDIM  128        // hidden (message MLP)
#define HRDIM  128        // hidden (readout)
#define KIN    136        // 2*S + 8
#define NSTEPS 5

static_assert(NE % 64 == 0, "edge grid exact");
static_assert(NF % 64 == 0, "factor grid exact");

typedef __attribute__((ext_vector_type(8))) short short8;   // 8 bf16 = 4 VGPRs
typedef __attribute__((ext_vector_type(4))) float f32x4;    // MFMA C/D

// ---------- helpers ----------
static __device__ __forceinline__ float bf2f(unsigned short u) {
    return __uint_as_float(((unsigned int)u) << 16);
}
static __device__ __forceinline__ unsigned short f2bf(float f) {
    unsigned int u = __float_as_uint(f);
    u += 0x7fffu + ((u >> 16) & 1u);          // round-to-nearest-even
    return (unsigned short)(u >> 16);
}
static __device__ __forceinline__ float sigm(float x) {
    x = fminf(fmaxf(x, -30.f), 30.f);
    return 1.f / (1.f + __expf(-x));
}
static __device__ __forceinline__ float tanh_f(float x) {
    x = fminf(fmaxf(x, -15.f), 15.f);
    float t = __expf(2.f * x);
    return (t - 1.f) / (t + 1.f);
}
// split f32 -> bf16 hi + bf16 lo (x ~= hi + lo, ~16 mantissa bits kept)
static __device__ __forceinline__ void split8(const float* x, short8& hi, short8& lo) {
    #pragma unroll
    for (int i = 0; i < 8; ++i) {
        unsigned short h = f2bf(x[i]);
        hi[i] = (short)h;
        lo[i] = (short)f2bf(x[i] - bf2f(h));
    }
}
static __device__ __forceinline__ void f4pair_to8(float4 a, float4 b, float* xv) {
    xv[0]=a.x; xv[1]=a.y; xv[2]=a.z; xv[3]=a.w;
    xv[4]=b.x; xv[5]=b.y; xv[6]=b.z; xv[7]=b.w;
}

__global__ void k_zero(float* __restrict__ p, int n) {
    int i = blockIdx.x * blockDim.x + threadIdx.x;
    int stride = gridDim.x * blockDim.x;
    for (; i < n; i += stride) p[i] = 0.f;
}

// ---------- CSR build over f2v_col (node-sorted edge order) ----------
__global__ void k_hist(const int* __restrict__ cols, int* __restrict__ cnt) {
    int e = blockIdx.x * 256 + threadIdx.x;      // grid exact: NE/256
    atomicAdd(&cnt[cols[e]], 1);
}
// exclusive scan of cnt[0..NN) -> off[0..NN]; cursor copy (cnt may alias cursor)
__global__ void k_scan(const int* cnt, int* off, int* cursor) {
    __shared__ int sbuf[1024];
    __shared__ int scarry;
    int tid = threadIdx.x;
    if (tid == 0) scarry = 0;
    __syncthreads();
    for (int base = 0; base < NN; base += 1024) {
        int i = base + tid;
        int v = (i < NN) ? cnt[i] : 0;
        sbuf[tid] = v;
        __syncthreads();
        for (int d = 1; d < 1024; d <<= 1) {
            int t = (tid >= d) ? sbuf[tid - d] : 0;
            __syncthreads();
            sbuf[tid] += t;
            __syncthreads();
        }
        int incl = sbuf[tid];
        int carry = scarry;
        if (i < NN) { int ex = carry + incl - v; off[i] = ex; cursor[i] = ex; }
        __syncthreads();
        if (tid == 1023) scarry = carry + incl;
        __syncthreads();
    }
    if (tid == 0) off[NN] = scarry;
}
__global__ void k_scatter(const int* __restrict__ cols, int* cursor, int* __restrict__ eid) {
    int e = blockIdx.x * 256 + threadIdx.x;      // grid exact
    int pos = atomicAdd(&cursor[cols[e]], 1);
    eid[pos] = e;
}

// ---------- weight transpose for readout (dst[k][j] = src[j][k]) ----------
#define NTR 2
struct TArgs {
    const float* src[NTR];
    float*       dst[NTR];
    int          R[NTR];
    int          C[NTR];
};
__global__ void k_transpose(TArgs a) {
    const int b = blockIdx.x;
    const float* s = a.src[b];
    float* d = a.dst[b];
    const int R = a.R[b], C = a.C[b], n = R * C;
    for (int i = threadIdx.x; i < n; i += blockDim.x) {
        int r = i / C, c = i % C;
        d[c * R + r] = s[i];
    }
}

// ---------- pack weights into B-fragment streams (hi/lo bf16) ----------
#define NPK 10
struct PArgs {
    const float*    src[NPK];
    unsigned short* hi[NPK];
    unsigned short* lo[NPK];
    int             N[NPK], K[NPK], CK[NPK];
};
__global__ void k_pack(PArgs a) {
    const int b = blockIdx.x;
    const float* s = a.src[b];
    unsigned short* ph = a.hi[b];
    unsigned short* pl = a.lo[b];
    const int N = a.N[b], K = a.K[b], CK = a.CK[b];
    const int NT = N >> 4;
    const int total = NT * CK * 512;
    for (int i = threadIdx.x; i < total; i += blockDim.x) {
        int j    = i & 7;
        int ln   = (i >> 3) & 63;
        int tile = i >> 9;
        int tn   = tile % NT;
        int ck   = tile / NT;
        int k = ck * 32 + ((ln >> 4) * 8) + j;
        int n = tn * 16 + (ln & 15);
        float f = (k < K) ? s[n * K + k] : 0.f;
        unsigned short h = f2bf(f);
        ph[i] = h;
        pl[i] = f2bf(f - bf2f(h));
    }
}

// bias sums for GRU r/z gates: o[j] = bih[j] + bhh[j], j in [0,192)
__global__ void k_bsum(const float* bih0, const float* bhh0, float* o0,
                       const float* bih1, const float* bhh1, float* o1) {
    int i = threadIdx.x;
    if (i < 192) { o0[i] = bih0[i] + bhh0[i]; o1[i] = bih1[i] + bhh1[i]; }
}

// ---------- f2v edge MLP: CSR-ordered, f32 em plain stores (NO atomics) ----------
// Block = 64 CSR slots, 128 threads = 2 waves; wave w owns slots [32w,32w+32)
// as two 16-row M-tiles. e = eid[slot]; r = e>>1 (f2v_row = repeat(arange F,2));
// c = f2v_col[e]. Stores per-edge messages (f32 — R17's bf16 quantization of
// ~16 summed messages cost 0.023 absmax) at em[slot]; var GRU reduces runs.
__global__ __launch_bounds__(128, 2)
void k_edge_f2v(const float* __restrict__ fac_h, const float* __restrict__ var_h,
                const int* __restrict__ eid, const int* __restrict__ cols,
                const float* __restrict__ feat,
                const unsigned short* __restrict__ w1h, const unsigned short* __restrict__ w1l,
                const unsigned short* __restrict__ w2h, const unsigned short* __restrict__ w2l,
                const unsigned short* __restrict__ w3h, const unsigned short* __restrict__ w3l,
                const float* __restrict__ b1, const float* __restrict__ b2,
                const float* __restrict__ b3,
                float* __restrict__ em)
{
    __shared__ unsigned short Hhi[64][136];
    __shared__ unsigned short Hlo[64][136];
    const int lane = threadIdx.x & 63;
    const int wv   = threadIdx.x >> 6;
    const int quad = lane >> 4;
    const int col  = lane & 15;
    int r[2], c[2];
    {
        int s0 = blockIdx.x * 64 + wv * 32 + col;
        int e0 = eid[s0], e1 = eid[s0 + 16];
        r[0] = e0 >> 1; c[0] = cols[e0];
        r[1] = e1 >> 1; c[1] = cols[e1];
    }

    // hoisted gathers
    float4 gR[2][4], gC[2][4], gFr[2], gFc[2];
    #pragma unroll
    for (int mt = 0; mt < 2; ++mt) {
        const float4* pr = (const float4*)(fac_h + (size_t)r[mt] * 64);
        const float4* pc = (const float4*)(var_h + (size_t)c[mt] * 64);
        gR[mt][0] = pr[quad * 2];     gR[mt][1] = pr[quad * 2 + 1];
        gR[mt][2] = pr[8 + quad * 2]; gR[mt][3] = pr[8 + quad * 2 + 1];
        gC[mt][0] = pc[quad * 2];     gC[mt][1] = pc[quad * 2 + 1];
        gC[mt][2] = pc[8 + quad * 2]; gC[mt][3] = pc[8 + quad * 2 + 1];
        gFr[mt] = *(const float4*)(feat + (size_t)r[mt] * 4);
        gFc[mt] = *(const float4*)(feat + (size_t)c[mt] * 4);
    }

    f32x4 acc[2][8];
    #pragma unroll
    for (int mt = 0; mt < 2; ++mt)
        #pragma unroll
        for (int t = 0; t < 8; ++t) acc[mt][t] = (f32x4){0.f, 0.f, 0.f, 0.f};

    // layer 1 (K padded 136->160, 5 chunks)
    #pragma unroll
    for (int ck = 0; ck < 5; ++ck) {
        short8 ahi[2], alo[2];
        #pragma unroll
        for (int mt = 0; mt < 2; ++mt) {
            float xv[8];
            if (ck < 2)      f4pair_to8(gR[mt][ck * 2], gR[mt][ck * 2 + 1], xv);
            else if (ck < 4) f4pair_to8(gC[mt][(ck - 2) * 2], gC[mt][(ck - 2) * 2 + 1], xv);
            else if (quad == 0) f4pair_to8(gFr[mt], gFc[mt], xv);
            else {
                for (int i = 0; i < 8; ++i) xv[i] = 0.f;
            }
            split8(xv, ahi[mt], alo[mt]);
        }
        const unsigned short* bh = w1h + (size_t)(ck * 8) * 512 + lane * 8;
        const unsigned short* bl = w1l + (size_t)(ck * 8) * 512 + lane * 8;
        #pragma unroll
        for (int tn = 0; tn < 8; ++tn) {
            short8 bhi = *(const short8*)(bh + tn * 512);
            short8 blo = *(const short8*)(bl + tn * 512);
            #pragma unroll
            for (int mt = 0; mt < 2; ++mt) {
                acc[mt][tn] = __builtin_amdgcn_mfma_f32_16x16x32_bf16(ahi[mt], bhi, acc[mt][tn], 0, 0, 0);
                acc[mt][tn] = __builtin_amdgcn_mfma_f32_16x16x32_bf16(ahi[mt], blo, acc[mt][tn], 0, 0, 0);
                acc[mt][tn] = __builtin_amdgcn_mfma_f32_16x16x32_bf16(alo[mt], bhi, acc[mt][tn], 0, 0, 0);
            }
        }
    }
    #pragma unroll
    for (int mt = 0; mt < 2; ++mt)
        #pragma unroll
        for (int tn = 0; tn < 8; ++tn) {
            float bias = b1[tn * 16 + col];
            #pragma unroll
            for (int rr = 0; rr < 4; ++rr) {
                float v = fmaxf(acc[mt][tn][rr] + bias, 0.f);
                int m = wv * 32 + mt * 16 + quad * 4 + rr;
                unsigned short h = f2bf(v);
                Hhi[m][tn * 16 + col] = h;
                Hlo[m][tn * 16 + col] = f2bf(v - bf2f(h));
            }
        }

    // layer 2
    #pragma unroll
    for (int mt = 0; mt < 2; ++mt)
        #pragma unroll
        for (int t = 0; t < 8; ++t) acc[mt][t] = (f32x4){0.f, 0.f, 0.f, 0.f};
    {
        const int m0 = wv * 32 + col;
        #pragma unroll
        for (int ck = 0; ck < 4; ++ck) {
            short8 ahi[2], alo[2];
            #pragma unroll
            for (int mt = 0; mt < 2; ++mt) {
                ahi[mt] = *(const short8*)(&Hhi[m0 + mt * 16][ck * 32 + quad * 8]);
                alo[mt] = *(const short8*)(&Hlo[m0 + mt * 16][ck * 32 + quad * 8]);
            }
            const unsigned short* bh = w2h + (size_t)(ck * 8) * 512 + lane * 8;
            const unsigned short* bl = w2l + (size_t)(ck * 8) * 512 + lane * 8;
            #pragma unroll
            for (int tn = 0; tn < 8; ++tn) {
                short8 bhi = *(const short8*)(bh + tn * 512);
                short8 blo = *(const short8*)(bl + tn * 512);
                #pragma unroll
                for (int mt = 0; mt < 2; ++mt) {
                    acc[mt][tn] = __builtin_amdgcn_mfma_f32_16x16x32_bf16(ahi[mt], bhi, acc[mt][tn], 0, 0, 0);
                    acc[mt][tn] = __builtin_amdgcn_mfma_f32_16x16x32_bf16(ahi[mt], blo, acc[mt][tn], 0, 0, 0);
                    acc[mt][tn] = __builtin_amdgcn_mfma_f32_16x16x32_bf16(alo[mt], bhi, acc[mt][tn], 0, 0, 0);
                }
            }
        }
    }
    #pragma unroll
    for (int mt = 0; mt < 2; ++mt)
        #pragma unroll
        for (int tn = 0; tn < 8; ++tn) {
            float bias = b2[tn * 16 + col];
            #pragma unroll
            for (int rr = 0; rr < 4; ++rr) {
                float v = fmaxf(acc[mt][tn][rr] + bias, 0.f);
                int m = wv * 32 + mt * 16 + quad * 4 + rr;
                unsigned short h = f2bf(v);
                Hhi[m][tn * 16 + col] = h;
                Hlo[m][tn * 16 + col] = f2bf(v - bf2f(h));
            }
        }

    // layer 3
    f32x4 a3[2][4];
    #pragma unroll
    for (int mt = 0; mt < 2; ++mt)
        #pragma unroll
        for (int t = 0; t < 4; ++t) a3[mt][t] = (f32x4){0.f, 0.f, 0.f, 0.f};
    {
        const int m0 = wv * 32 + col;
        #pragma unroll
        for (int ck = 0; ck < 4; ++ck) {
            short8 ahi[2], alo[2];
            #pragma unroll
            for (int mt = 0; mt < 2; ++mt) {
                ahi[mt] = *(const short8*)(&Hhi[m0 + mt * 16][ck * 32 + quad * 8]);
                alo[mt] = *(const short8*)(&Hlo[m0 + mt * 16][ck * 32 + quad * 8]);
            }
            const unsigned short* bh = w3h + (size_t)(ck * 4) * 512 + lane * 8;
            const unsigned short* bl = w3l + (size_t)(ck * 4) * 512 + lane * 8;
            #pragma unroll
            for (int tn = 0; tn < 4; ++tn) {
                short8 bhi = *(const short8*)(bh + tn * 512);
                short8 blo = *(const short8*)(bl + tn * 512);
                #pragma unroll
                for (int mt = 0; mt < 2; ++mt) {
                    a3[mt][tn] = __builtin_amdgcn_mfma_f32_16x16x32_bf16(ahi[mt], bhi, a3[mt][tn], 0, 0, 0);
                    a3[mt][tn] = __builtin_amdgcn_mfma_f32_16x16x32_bf16(ahi[mt], blo, a3[mt][tn], 0, 0, 0);
                    a3[mt][tn] = __builtin_amdgcn_mfma_f32_16x16x32_bf16(alo[mt], bhi, a3[mt][tn], 0, 0, 0);
                }
            }
        }
    }
    // epilogue: bias + f32 plain stores at the linear CSR slot (no atomics)
    #pragma unroll
    for (int mt = 0; mt < 2; ++mt) {
        int sD = blockIdx.x * 64 + wv * 32 + mt * 16 + quad * 4;
        #pragma unroll
        for (int tn = 0; tn < 4; ++tn) {
            float bias = b3[tn * 16 + col];
            #pragma unroll
            for (int rr = 0; rr < 4; ++rr)
                em[(size_t)(sD + rr) * 64 + tn * 16 + col] = a3[mt][tn][rr] + bias;
        }
    }
}

// ---------- v2f edge MLP: structured cols, pair-sum, f32 plain stores ----------
// v2f_col = e>>1: block's 64 edges = 32 consecutive factors, pairs (2f,2f+1)
// land in ADJACENT D regs of the same lane -> in-register sum, direct store.
__global__ __launch_bounds__(128, 2)
void k_edge_v2f(const float* __restrict__ var_h, const float* __restrict__ fac_h,
                const int* __restrict__ rows,
                const float* __restrict__ feat,
                const unsigned short* __restrict__ w1h, const unsigned short* __restrict__ w1l,
                const unsigned short* __restrict__ w2h, const unsigned short* __restrict__ w2l,
                const unsigned short* __restrict__ w3h, const unsigned short* __restrict__ w3l,
                const float* __restrict__ b1, const float* __restrict__ b2,
                const float* __restrict__ b3,
                float* __restrict__ nm)
{
    __shared__ unsigned short Hhi[64][136];
    __shared__ unsigned short Hlo[64][136];
    const int lane = threadIdx.x & 63;
    const int wv   = threadIdx.x >> 6;
    const int quad = lane >> 4;
    const int col  = lane & 15;
    int r[2], c[2];
    {
        int e0 = blockIdx.x * 64 + wv * 32 + col;
        r[0] = rows[e0];      c[0] = e0 >> 1;
        r[1] = rows[e0 + 16]; c[1] = (e0 + 16) >> 1;
    }

    float4 gR[2][4], gC[2][4], gFr[2], gFc[2];
    #pragma unroll
    for (int mt = 0; mt < 2; ++mt) {
        const float4* pr = (const float4*)(var_h + (size_t)r[mt] * 64);
        const float4* pc = (const float4*)(fac_h + (size_t)c[mt] * 64);
        gR[mt][0] = pr[quad * 2];     gR[mt][1] = pr[quad * 2 + 1];
        gR[mt][2] = pr[8 + quad * 2]; gR[mt][3] = pr[8 + quad * 2 + 1];
        gC[mt][0] = pc[quad * 2];     gC[mt][1] = pc[quad * 2 + 1];
        gC[mt][2] = pc[8 + quad * 2]; gC[mt][3] = pc[8 + quad * 2 + 1];
        gFr[mt] = *(const float4*)(feat + (size_t)r[mt] * 4);
        gFc[mt] = *(const float4*)(feat + (size_t)c[mt] * 4);
    }

    f32x4 acc[2][8];
    #pragma unroll
    for (int mt = 0; mt < 2; ++mt)
        #pragma unroll
        for (int t = 0; t < 8; ++t) acc[mt][t] = (f32x4){0.f, 0.f, 0.f, 0.f};

    #pragma unroll
    for (int ck = 0; ck < 5; ++ck) {
        short8 ahi[2], alo[2];
        #pragma unroll
        for (int mt = 0; mt < 2; ++mt) {
            float xv[8];
            if (ck < 2)      f4pair_to8(gR[mt][ck * 2], gR[mt][ck * 2 + 1], xv);
            else if (ck < 4) f4pair_to8(gC[mt][(ck - 2) * 2], gC[mt][(ck - 2) * 2 + 1], xv);
            else if (quad == 0) f4pair_to8(gFr[mt], gFc[mt], xv);
            else {
                for (int i = 0; i < 8; ++i) xv[i] = 0.f;
            }
            split8(xv, ahi[mt], alo[mt]);
        }
        const unsigned short* bh = w1h + (size_t)(ck * 8) * 512 + lane * 8;
        const unsigned short* bl = w1l + (size_t)(ck * 8) * 512 + lane * 8;
        #pragma unroll
        for (int tn = 0; tn < 8; ++tn) {
            short8 bhi = *(const short8*)(bh + tn * 512);
            short8 blo = *(const short8*)(bl + tn * 512);
            #pragma unroll
            for (int mt = 0; mt < 2; ++mt) {
                acc[mt][tn] = __builtin_amdgcn_mfma_f32_16x16x32_bf16(ahi[mt], bhi, acc[mt][tn], 0, 0, 0);
                acc[mt][tn] = __builtin_amdgcn_mfma_f32_16x16x32_bf16(ahi[mt], blo, acc[mt][tn], 0, 0, 0);
                acc[mt][tn] = __builtin_amdgcn_mfma_f32_16x16x32_bf16(alo[mt], bhi, acc[mt][tn], 0, 0, 0);
            }
        }
    }
    #pragma unroll
    for (int mt = 0; mt < 2; ++mt)
        #pragma unroll
        for (int tn = 0; tn < 8; ++tn) {
            float bias = b1[tn * 16 + col];
            #pragma unroll
            for (int rr = 0; rr < 4; ++rr) {
                float v = fmaxf(acc[mt][tn][rr] + bias, 0.f);
                int m = wv * 32 + mt * 16 + quad * 4 + rr;
                unsigned short h = f2bf(v);
                Hhi[m][tn * 16 + col] = h;
                Hlo[m][tn * 16 + col] = f2bf(v - bf2f(h));
            }
        }

    #pragma unroll
    for (int mt = 0; mt < 2; ++mt)
        #pragma unroll
        for (int t = 0; t < 8; ++t) acc[mt][t] = (f32x4){0.f, 0.f, 0.f, 0.f};
    {
        const int m0 = wv * 32 + col;
        #pragma unroll
        for (int ck = 0; ck < 4; ++ck) {
            short8 ahi[2], alo[2];
            #pragma unroll
            for (int mt = 0; mt < 2; ++mt) {
                ahi[mt] = *(const short8*)(&Hhi[m0 + mt * 16][ck * 32 + quad * 8]);
                alo[mt] = *(const short8*)(&Hlo[m0 + mt * 16][ck * 32 + quad * 8]);
            }
            const unsigned short* bh = w2h + (size_t)(ck * 8) * 512 + lane * 8;
            const unsigned short* bl = w2l + (size_t)(ck * 8) * 512 + lane * 8;
            #pragma unroll
            for (int tn = 0; tn < 8; ++tn) {
                short8 bhi = *(const short8*)(bh + tn * 512);
                short8 blo = *(const short8*)(bl + tn * 512);
                #pragma unroll
                for (int mt = 0; mt < 2; ++mt) {
                    acc[mt][tn] = __builtin_amdgcn_mfma_f32_16x16x32_bf16(ahi[mt], bhi, acc[mt][tn], 0, 0, 0);
                    acc[mt][tn] = __builtin_amdgcn_mfma_f32_16x16x32_bf16(ahi[mt], blo, acc[mt][tn], 0, 0, 0);
                    acc[mt][tn] = __builtin_amdgcn_mfma_f32_16x16x32_bf16(alo[mt], bhi, acc[mt][tn], 0, 0, 0);
                }
            }
        }
    }
    #pragma unroll
    for (int mt = 0; mt < 2; ++mt)
        #pragma unroll
        for (int tn = 0; tn < 8; ++tn) {
            float bias = b2[tn * 16 + col];
            #pragma unroll
            for (int rr = 0; rr < 4; ++rr) {
                float v = fmaxf(acc[mt][tn][rr] + bias, 0.f);
                int m = wv * 32 + mt * 16 + quad * 4 + rr;
                unsigned short h = f2bf(v);
                Hhi[m][tn * 16 + col] = h;
                Hlo[m][tn * 16 + col] = f2bf(v - bf2f(h));
            }
        }

    f32x4 a3[2][4];
    #pragma unroll
    for (int mt = 0; mt < 2; ++mt)
        #pragma unroll
        for (int t = 0; t < 4; ++t) a3[mt][t] = (f32x4){0.f, 0.f, 0.f, 0.f};
    {
        const int m0 = wv * 32 + col;
        #pragma unroll
        for (int ck = 0; ck < 4; ++ck) {
            short8 ahi[2], alo[2];
            #pragma unroll
            for (int mt = 0; mt < 2; ++mt) {
                ahi[mt] = *(const short8*)(&Hhi[m0 + mt * 16][ck * 32 + quad * 8]);
                alo[mt] = *(const short8*)(&Hlo[m0 + mt * 16][ck * 32 + quad * 8]);
            }
            const unsigned short* bh = w3h + (size_t)(ck * 4) * 512 + lane * 8;
            const unsigned short* bl = w3l + (size_t)(ck * 4) * 512 + lane * 8;
            #pragma unroll
            for (int tn = 0; tn < 4; ++tn) {
                short8 bhi = *(const short8*)(bh + tn * 512);
                short8 blo = *(const short8*)(bl + tn * 512);
                #pragma unroll
                for (int mt = 0; mt < 2; ++mt) {
                    a3[mt][tn] = __builtin_amdgcn_mfma_f32_16x16x32_bf16(ahi[mt], bhi, a3[mt][tn], 0, 0, 0);
                    a3[mt][tn] = __builtin_amdgcn_mfma_f32_16x16x32_bf16(ahi[mt], blo, a3[mt][tn], 0, 0, 0);
                    a3[mt][tn] = __builtin_amdgcn_mfma_f32_16x16x32_bf16(alo[mt], bhi, a3[mt][tn], 0, 0, 0);
                }
            }
        }
    }
    // epilogue: per-edge bias, in-register pair sum, plain stores (no atomics)
    #pragma unroll
    for (int mt = 0; mt < 2; ++mt) {
        int fb = 32 * blockIdx.x + 16 * wv + 8 * mt + 2 * quad;
        #pragma unroll
        for (int tn = 0; tn < 4; ++tn) {
            float bias = b3[tn * 16 + col];
            float s01 = (a3[mt][tn][0] + bias) + (a3[mt][tn][1] + bias);
            float s23 = (a3[mt][tn][2] + bias) + (a3[mt][tn][3] + bias);
            nm[(size_t)fb * 64 + tn * 16 + col] = s01;
            nm[(size_t)(fb + 1) * 64 + tn * 16 + col] = s23;
        }
    }
}

// ---------- var GRU: CSR-reduce f32 em runs, then MFMA GRU ----------
__global__ __launch_bounds__(128, 2)
void k_gru_var(const float* __restrict__ em, const int* __restrict__ off,
               const unsigned short* __restrict__ wih_h, const unsigned short* __restrict__ wih_l,
               const unsigned short* __restrict__ whh_h, const unsigned short* __restrict__ whh_l,
               const float* __restrict__ bsum,
               const float* __restrict__ bih, const float* __restrict__ bhh,
               float* __restrict__ hst, int count)
{
    __shared__ float Hs[64][68];
    const int lane = threadIdx.x & 63;
    const int wv   = threadIdx.x >> 6;
    const int quad = lane >> 4;
    const int col  = lane & 15;
    const int base = blockIdx.x * 64;

    // message sums (CSR runs, f32) + h loads
    float ms[2][16];
    float4 ah[2][4];
    #pragma unroll
    for (int mt = 0; mt < 2; ++mt) {
        #pragma unroll
        for (int i = 0; i < 16; ++i) ms[mt][i] = 0.f;
        int na = base + wv * 32 + mt * 16 + col;
        na = na < count ? na : count - 1;
        int p0 = off[na], p1 = off[na + 1];
        for (int p = p0; p < p1; ++p) {
            const float4* q = (const float4*)(em + (size_t)p * 64);
            float4 a0 = q[quad * 2], a1 = q[quad * 2 + 1];
            float4 b0 = q[8 + quad * 2], b1v = q[8 + quad * 2 + 1];
            ms[mt][0] += a0.x; ms[mt][1] += a0.y; ms[mt][2] += a0.z; ms[mt][3] += a0.w;
            ms[mt][4] += a1.x; ms[mt][5] += a1.y; ms[mt][6] += a1.z; ms[mt][7] += a1.w;
            ms[mt][8]  += b0.x; ms[mt][9]  += b0.y; ms[mt][10] += b0.z; ms[mt][11] += b0.w;
            ms[mt][12] += b1v.x; ms[mt][13] += b1v.y; ms[mt][14] += b1v.z; ms[mt][15] += b1v.w;
        }
        const float4* ph = (const float4*)(hst + (size_t)na * 64);
        ah[mt][0] = ph[quad * 2];     ah[mt][1] = ph[quad * 2 + 1];
        ah[mt][2] = ph[8 + quad * 2]; ah[mt][3] = ph[8 + quad * 2 + 1];
    }
    // stage h into LDS (wave-private rows)
    #pragma unroll
    for (int mt = 0; mt < 2; ++mt) {
        int rowl = wv * 32 + mt * 16 + col;
        *(float4*)(&Hs[rowl][quad * 8])          = ah[mt][0];
        *(float4*)(&Hs[rowl][quad * 8 + 4])      = ah[mt][1];
        *(float4*)(&Hs[rowl][32 + quad * 8])     = ah[mt][2];
        *(float4*)(&Hs[rowl][32 + quad * 8 + 4]) = ah[mt][3];
    }

    f32x4 rz[2][8], ni[2][4], nh[2][4];
    #pragma unroll
    for (int mt = 0; mt < 2; ++mt) {
        #pragma unroll
        for (int t = 0; t < 8; ++t) rz[mt][t] = (f32x4){0.f, 0.f, 0.f, 0.f};
        #pragma unroll
        for (int t = 0; t < 4; ++t) {
            ni[mt][t] = (f32x4){0.f, 0.f, 0.f, 0.f};
            nh[mt][t] = (f32x4){0.f, 0.f, 0.f, 0.f};
        }
    }

    #pragma unroll
    for (int ck = 0; ck < 2; ++ck) {
        short8 mhi[2], mlo[2], hhi[2], hlo[2];
        #pragma unroll
        for (int mt = 0; mt < 2; ++mt) {
            split8(&ms[mt][ck * 8], mhi[mt], mlo[mt]);
            float xv[8];
            f4pair_to8(ah[mt][ck * 2], ah[mt][ck * 2 + 1], xv);
            split8(xv, hhi[mt], hlo[mt]);
        }
        const unsigned short* ih = wih_h + (size_t)(ck * 12) * 512 + lane * 8;
        const unsigned short* il = wih_l + (size_t)(ck * 12) * 512 + lane * 8;
        const unsigned short* hh = whh_h + (size_t)(ck * 12) * 512 + lane * 8;
        const unsigned short* hl = whh_l + (size_t)(ck * 12) * 512 + lane * 8;
        #pragma unroll
        for (int tn = 0; tn < 8; ++tn) {
            short8 bihh = *(const short8*)(ih + tn * 512);
            short8 bihl = *(const short8*)(il + tn * 512);
            short8 bhhh = *(const short8*)(hh + tn * 512);
            short8 bhhl = *(const short8*)(hl + tn * 512);
            #pragma unroll
            for (int mt = 0; mt < 2; ++mt) {
                rz[mt][tn] = __builtin_amdgcn_mfma_f32_16x16x32_bf16(mhi[mt], bihh, rz[mt][tn], 0, 0, 0);
                rz[mt][tn] = __builtin_amdgcn_mfma_f32_16x16x32_bf16(mhi[mt], bihl, rz[mt][tn], 0, 0, 0);
                rz[mt][tn] = __builtin_amdgcn_mfma_f32_16x16x32_bf16(mlo[mt], bihh, rz[mt][tn], 0, 0, 0);
                rz[mt][tn] = __builtin_amdgcn_mfma_f32_16x16x32_bf16(hhi[mt], bhhh, rz[mt][tn], 0, 0, 0);
                rz[mt][tn] = __builtin_amdgcn_mfma_f32_16x16x32_bf16(hhi[mt], bhhl, rz[mt][tn], 0, 0, 0);
                rz[mt][tn] = __builtin_amdgcn_mfma_f32_16x16x32_bf16(hlo[mt], bhhh, rz[mt][tn], 0, 0, 0);
            }
        }
        #pragma unroll
        for (int tn = 8; tn < 12; ++tn) {
            short8 bihh = *(const short8*)(ih + tn * 512);
            short8 bihl = *(const short8*)(il + tn * 512);
            short8 bhhh = *(const short8*)(hh + tn * 512);
            short8 bhhl = *(const short8*)(hl + tn * 512);
            #pragma unroll
            for (int mt = 0; mt < 2; ++mt) {
                ni[mt][tn - 8] = __builtin_amdgcn_mfma_f32_16x16x32_bf16(mhi[mt], bihh, ni[mt][tn - 8], 0, 0, 0);
                ni[mt][tn - 8] = __builtin_amdgcn_mfma_f32_16x16x32_bf16(mhi[mt], bihl, ni[mt][tn - 8], 0, 0, 0);
                ni[mt][tn - 8] = __builtin_amdgcn_mfma_f32_16x16x32_bf16(mlo[mt], bihh, ni[mt][tn - 8], 0, 0, 0);
                nh[mt][tn - 8] = __builtin_amdgcn_mfma_f32_16x16x32_bf16(hhi[mt], bhhh, nh[mt][tn - 8], 0, 0, 0);
                nh[mt][tn - 8] = __builtin_amdgcn_mfma_f32_16x16x32_bf16(hhi[mt], bhhl, nh[mt][tn - 8], 0, 0, 0);
                nh[mt][tn - 8] = __builtin_amdgcn_mfma_f32_16x16x32_bf16(hlo[mt], bhhh, nh[mt][tn - 8], 0, 0, 0);
            }
        }
    }

    #pragma unroll
    for (int mt = 0; mt < 2; ++mt) {
        #pragma unroll
        for (int rr = 0; rr < 4; ++rr) {
            int rowl = wv * 32 + mt * 16 + quad * 4 + rr;
            int grow = base + rowl;
            bool ok = grow < count;
            #pragma unroll
            for (int t = 0; t < 4; ++t) {
                int g = t * 16 + col;
                float rv = sigm(rz[mt][t][rr] + bsum[g]);
                float zv = sigm(rz[mt][4 + t][rr] + bsum[64 + g]);
                float nv = tanh_f(ni[mt][t][rr] + bih[128 + g]
                                  + rv * (nh[mt][t][rr] + bhh[128 + g]));
                if (ok) {
                    float ho = Hs[rowl][g];
                    hst[(size_t)grow * 64 + g] = (1.f - zv) * nv + zv * ho;
                }
            }
        }
    }
}

// ---------- fac GRU: reads plain-stored nm rows ----------
__global__ __launch_bounds__(128, 2)
void k_gru_fac(const float* __restrict__ nm,
               const unsigned short* __restrict__ wih_h, const unsigned short* __restrict__ wih_l,
               const unsigned short* __restrict__ whh_h, const unsigned short* __restrict__ whh_l,
               const float* __restrict__ bsum,
               const float* __restrict__ bih, const float* __restrict__ bhh,
               float* __restrict__ hst, int count)
{
    __shared__ float Hs[64][68];
    const int lane = threadIdx.x & 63;
    const int wv   = threadIdx.x >> 6;
    const int quad = lane >> 4;
    const int col  = lane & 15;
    const int base = blockIdx.x * 64;

    float4 am[2][4], ah[2][4];
    #pragma unroll
    for (int mt = 0; mt < 2; ++mt) {
        int ra = base + wv * 32 + mt * 16 + col;
        ra = ra < count ? ra : count - 1;
        const float4* pm = (const float4*)(nm + (size_t)ra * 64);
        const float4* ph = (const float4*)(hst + (size_t)ra * 64);
        am[mt][0] = pm[quad * 2];     am[mt][1] = pm[quad * 2 + 1];
        am[mt][2] = pm[8 + quad * 2]; am[mt][3] = pm[8 + quad * 2 + 1];
        ah[mt][0] = ph[quad * 2];     ah[mt][1] = ph[quad * 2 + 1];
        ah[mt][2] = ph[8 + quad * 2]; ah[mt][3] = ph[8 + quad * 2 + 1];
    }
    #pragma unroll
    for (int mt = 0; mt < 2; ++mt) {
        int rowl = wv * 32 + mt * 16 + col;
        *(float4*)(&Hs[rowl][quad * 8])          = ah[mt][0];
        *(float4*)(&Hs[rowl][quad * 8 + 4])      = ah[mt][1];
        *(float4*)(&Hs[rowl][32 + quad * 8])     = ah[mt][2];
        *(float4*)(&Hs[rowl][32 + quad * 8 + 4]) = ah[mt][3];
    }

    f32x4 rz[2][8], ni[2][4], nh[2][4];
    #pragma unroll
    for (int mt = 0; mt < 2; ++mt) {
        #pragma unroll
        for (int t = 0; t < 8; ++t) rz[mt][t] = (f32x4){0.f, 0.f, 0.f, 0.f};
        #pragma unroll
        for (int t = 0; t < 4; ++t) {
            ni[mt][t] = (f32x4){0.f, 0.f, 0.f, 0.f};
            nh[mt][t] = (f32x4){0.f, 0.f, 0.f, 0.f};
        }
    }

    #pragma unroll
    for (int ck = 0; ck < 2; ++ck) {
        short8 mhi[2], mlo[2], hhi[2], hlo[2];
        #pragma unroll
        for (int mt = 0; mt < 2; ++mt) {
            float xv[8];
            f4pair_to8(am[mt][ck * 2], am[mt][ck * 2 + 1], xv);
            split8(xv, mhi[mt], mlo[mt]);
            f4pair_to8(ah[mt][ck * 2], ah[mt][ck * 2 + 1], xv);
            split8(xv, hhi[mt], hlo[mt]);
        }
        const unsigned short* ih = wih_h + (size_t)(ck * 12) * 512 + lane * 8;
        const unsigned short* il = wih_l + (size_t)(ck * 12) * 512 + lane * 8;
        const unsigned short* hh = whh_h + (size_t)(ck * 12) * 512 + lane * 8;
        const unsigned short* hl = whh_l + (size_t)(ck * 12) * 512 + lane * 8;
        #pragma unroll
        for (int tn = 0; tn < 8; ++tn) {
            short8 bihh = *(const short8*)(ih + tn * 512);
            short8 bihl = *(const short8*)(il + tn * 512);
            short8 bhhh = *(const short8*)(hh + tn * 512);
            short8 bhhl = *(const short8*)(hl + tn * 512);
            #pragma unroll
            for (int mt = 0; mt < 2; ++mt) {
                rz[mt][tn] = __builtin_amdgcn_mfma_f32_16x16x32_bf16(mhi[mt], bihh, rz[mt][tn], 0, 0, 0);
                rz[mt][tn] = __builtin_amdgcn_mfma_f32_16x16x32_bf16(mhi[mt], bihl, rz[mt][tn], 0, 0, 0);
                rz[mt][tn] = __builtin_amdgcn_mfma_f32_16x16x32_bf16(mlo[mt], bihh, rz[mt][tn], 0, 0, 0);
                rz[mt][tn] = __builtin_amdgcn_mfma_f32_16x16x32_bf16(hhi[mt], bhhh, rz[mt][tn], 0, 0, 0);
                rz[mt][tn] = __builtin_amdgcn_mfma_f32_16x16x32_bf16(hhi[mt], bhhl, rz[mt][tn], 0, 0, 0);
                rz[mt][tn] = __builtin_amdgcn_mfma_f32_16x16x32_bf16(hlo[mt], bhhh, rz[mt][tn], 0, 0, 0);
            }
        }
        #pragma unroll
        for (int tn = 8; tn < 12; ++tn) {
            short8 bihh = *(const short8*)(ih + tn * 512);
            short8 bihl = *(const short8*)(il + tn * 512);
            short8 bhhh = *(const short8*)(hh + tn * 512);
            short8 bhhl = *(const short8*)(hl + tn * 512);
            #pragma unroll
            for (int mt = 0; mt < 2; ++mt) {
                ni[mt][tn - 8] = __builtin_amdgcn_mfma_f32_16x16x32_bf16(mhi[mt], bihh, ni[mt][tn - 8], 0, 0, 0);
                ni[mt][tn - 8] = __builtin_amdgcn_mfma_f32_16x16x32_bf16(mhi[mt], bihl, ni[mt][tn - 8], 0, 0, 0);
                ni[mt][tn - 8] = __builtin_amdgcn_mfma_f32_16x16x32_bf16(mlo[mt], bihh, ni[mt][tn - 8], 0, 0, 0);
                nh[mt][tn - 8] = __builtin_amdgcn_mfma_f32_16x16x32_bf16(hhi[mt], bhhh, nh[mt][tn - 8], 0, 0, 0);
                nh[mt][tn - 8] = __builtin_amdgcn_mfma_f32_16x16x32_bf16(hhi[mt], bhhl, nh[mt][tn - 8], 0, 0, 0);
                nh[mt][tn - 8] = __builtin_amdgcn_mfma_f32_16x16x32_bf16(hlo[mt], bhhh, nh[mt][tn - 8], 0, 0, 0);
            }
        }
    }

    #pragma unroll
    for (int mt = 0; mt < 2; ++mt) {
        #pragma unroll
        for (int rr = 0; rr < 4; ++rr) {
            int rowl = wv * 32 + mt * 16 + quad * 4 + rr;
            int grow = base + rowl;
            bool ok = grow < count;
            #pragma unroll
            for (int t = 0; t < 4; ++t) {
                int g = t * 16 + col;
                float rv = sigm(rz[mt][t][rr] + bsum[g]);
                float zv = sigm(rz[mt][4 + t][rr] + bsum[64 + g]);
                float nv = tanh_f(ni[mt][t][rr] + bih[128 + g]
                                  + rv * (nh[mt][t][rr] + bhh[128 + g]));
                if (ok) {
                    float ho = Hs[rowl][g];
                    hst[(size_t)grow * 64 + g] = (1.f - zv) * nv + zv * ho;
                }
            }
        }
    }
}

// ---------- readout (unchanged) ----------
__global__ __launch_bounds__(256, 3)
void k_readout(const float* __restrict__ vh,
               const float* __restrict__ w1t, const float* __restrict__ b1,
               const float* __restrict__ w2t, const float* __restrict__ b2,
               const float* __restrict__ w3, const float* __restrict__ b3,
               float* __restrict__ out)
{
    __shared__ float H[HRDIM][64];
    const int lane = threadIdx.x & 63;
    const int wv   = __builtin_amdgcn_readfirstlane(threadIdx.x >> 6);
    const int n0 = blockIdx.x * 64 + lane;
    const int n  = n0 < NN ? n0 : NN - 1;
    const float4* px = (const float4*)(vh + (size_t)n * 64);

    const int j1 = 32 * wv;
    float acc[32];
    #pragma unroll
    for (int j = 0; j < 32; ++j) acc[j] = b1[j1 + j];
    #pragma unroll 4
    for (int q = 0; q < 16; ++q) {
        float4 x4 = px[q];
        const float* wa = w1t + (4 * q + 0) * HRDIM + j1;
        const float* wb = w1t + (4 * q + 1) * HRDIM + j1;
        const float* wc = w1t + (4 * q + 2) * HRDIM + j1;
        const float* wd = w1t + (4 * q + 3) * HRDIM + j1;
        #pragma unroll
        for (int j = 0; j < 32; ++j) {
            acc[j] = fmaf(wa[j], x4.x, acc[j]);
            acc[j] = fmaf(wb[j], x4.y, acc[j]);
            acc[j] = fmaf(wc[j], x4.z, acc[j]);
            acc[j] = fmaf(wd[j], x4.w, acc[j]);
        }
    }
    #pragma unroll
    for (int j = 0; j < 32; ++j) H[j1 + j][lane] = fmaxf(acc[j], 0.f);
    __syncthreads();

    #pragma unroll
    for (int j = 0; j < 32; ++j) acc[j] = b2[j1 + j];
    #pragma unroll 4
    for (int k = 0; k < HRDIM; ++k) {
        float xk = H[k][lane];
        const float* wr = w2t + k * HRDIM + j1;
        #pragma unroll
        for (int j = 0; j < 32; ++j)
            acc[j] = fmaf(wr[j], xk, acc[j]);
    }
    __syncthreads();
    #pragma unroll
    for (int j = 0; j < 32; ++j) H[j1 + j][lane] = fmaxf(acc[j], 0.f);
    __syncthreads();

    if (wv == 0 && n0 < NN) {
        float l0 = b3[0], l1 = b3[1];
        #pragma unroll 8
        for (int k = 0; k < HRDIM; ++k) {
            float hk = H[k][lane];
            l0 = fmaf(w3[k],         hk, l0);
            l1 = fmaf(w3[HRDIM + k], hk, l1);
        }
        float mx = fmaxf(l0, l1);
        float e0 = __expf(l0 - mx), e1 = __expf(l1 - mx);
        float inv = 1.f / (e0 + e1);
        out[2 * n + 0] = e0 * inv;
        out[2 * n + 1] = e1 * inv;
    }
}

// ---------- host ----------
extern "C" void kernel_launch(void* const* d_in, const int* in_sizes, int n_in,
                              void* d_out, int out_size, void* d_ws, size_t ws_size,
                              hipStream_t stream)
{
    // ws (f32 units), total 16,344,256 f32 = 65.38 MB (R1's layout ran at 65.4 MB)
    float* var_h = (float*)d_ws;                       //   640,000
    float* fac_h = var_h + 640000;                     // 5,120,000
    float* em    = fac_h + 5120000;                    // 10,240,000 f32 [NE,64]
    float* nm    = em;                                 //   aliased (phase-disjoint)
    float* ro_t  = em + 10240000;                      //    24,576
    float* bsum  = ro_t + 24576;                       //       384
    unsigned short* pk = (unsigned short*)(bsum + 384);// 278,528 u16
    int*   ioff  = (int*)(pk + 278528);                //  10,016 ints
    int*   icur  = ioff + 10016;                       //  10,016 ints
    int*   ieid  = icur + 10016;                       // 160,000 ints

    const int*   f2v_col  = (const int*)d_in[1];
    const int*   v2f_row  = (const int*)d_in[2];
    const float* f2v_feat = (const float*)d_in[4];
    const float* v2f_feat = (const float*)d_in[5];
    const float* W[26];
    for (int j = 0; j < 26; ++j) W[j] = (const float*)d_in[6 + j];
    // W: 0..5 f2v MLP, 6..11 v2f MLP, 12..15 gf GRU, 16..19 gv GRU, 20..25 readout

    TArgs ta;
    float* T[NTR];
    {
        const float* src[NTR] = { W[20], W[22] };
        int R[NTR] = { HRDIM, HRDIM };
        int C[NTR] = { SDIM, HRDIM };
        size_t off = 0;
        for (int t = 0; t < NTR; ++t) {
            ta.src[t] = src[t]; ta.R[t] = R[t]; ta.C[t] = C[t];
            T[t] = ro_t + off; ta.dst[t] = T[t];
            off += (size_t)R[t] * C[t];
        }
    }
    unsigned short* P[12];
    unsigned short* G[8];
    {
        size_t off = 0;
        int esz[3] = { 20480, 16384, 8192 };
        for (int d = 0; d < 2; ++d)
            for (int m = 0; m < 3; ++m) {
                P[d * 6 + m * 2 + 0] = pk + off; off += esz[m];
                P[d * 6 + m * 2 + 1] = pk + off; off += esz[m];
            }
        for (int t = 0; t < 8; ++t) { G[t] = pk + off; off += 12288; }
    }
    PArgs pa;
    {
        const float* src[NPK] = { W[0], W[2], W[4], W[6], W[8], W[10],
                                  W[12], W[13], W[16], W[17] };
        int N[NPK]  = { HMDIM, HMDIM, SDIM,  HMDIM, HMDIM, SDIM,  192, 192, 192, 192 };
        int K[NPK]  = { KIN,   HMDIM, HMDIM, KIN,   HMDIM, HMDIM, SDIM, SDIM, SDIM, SDIM };
        int CK[NPK] = { 5,     4,     4,     5,     4,     4,     2,   2,   2,   2 };
        unsigned short* hi[NPK] = { P[0], P[2], P[4], P[6], P[8], P[10],
                                    G[0], G[2], G[4], G[6] };
        unsigned short* lo[NPK] = { P[1], P[3], P[5], P[7], P[9], P[11],
                                    G[1], G[3], G[5], G[7] };
        for (int t = 0; t < NPK; ++t) {
            pa.src[t] = src[t]; pa.N[t] = N[t]; pa.K[t] = K[t]; pa.CK[t] = CK[t];
            pa.hi[t] = hi[t];   pa.lo[t] = lo[t];
        }
    }
    k_transpose<<<NTR, 256, 0, stream>>>(ta);
    k_pack<<<NPK, 256, 0, stream>>>(pa);
    k_bsum<<<1, 256, 0, stream>>>(W[14], W[15], bsum, W[18], W[19], bsum + 192);
    k_zero<<<512, 256, 0, stream>>>(var_h, 640000 + 5120000);  // states only
    k_zero<<<40, 256, 0, stream>>>((float*)icur, NN);          // CSR counts
    // CSR over f2v_col
    k_hist<<<NE / 256, 256, 0, stream>>>(f2v_col, icur);
    k_scan<<<1, 1024, 0, stream>>>(icur, ioff, icur);
    k_scatter<<<NE / 256, 256, 0, stream>>>(f2v_col, icur, ieid);

    for (int s = 0; s < NSTEPS; ++s) {
        // fac -> var: per-edge messages (f32) in CSR order, then var GRU reduce
        k_edge_f2v<<<NE / 64, 128, 0, stream>>>(
            fac_h, var_h, ieid, f2v_col, f2v_feat,
            P[0], P[1], P[2], P[3], P[4], P[5],
            W[1], W[3], W[5], em);
        k_gru_var<<<(NN + 63) / 64, 128, 0, stream>>>(
            em, ioff, G[0], G[1], G[2], G[3], bsum, W[14], W[15], var_h, NN);
        // var -> fac: pair-summed factor messages (plain f32 stores), fac GRU
        k_edge_v2f<<<NE / 64, 128, 0, stream>>>(
            var_h, fac_h, v2f_row, v2f_feat,
            P[6], P[7], P[8], P[9], P[10], P[11],
            W[7], W[9], W[11], nm);
        k_gru_fac<<<NF / 64, 128, 0, stream>>>(
            nm, G[4], G[5], G[6], G[7], bsum + 192, W[18], W[19], fac_h, NF);
    }
    k_readout<<<(NN + 63) / 64, 256, 0, stream>>>(
        var_h, T[0], W[21], T[1], W[23], W[24], W[25],
        (float*)d_out);
}

// Round 19
// 1426.830 us; speedup vs baseline: 1.1251x; 1.1251x over previous
//
#include <hip/hip_runtime.h>

// Problem constants (fixed by reference setup)
#define NN     10000      // variable nodes
#define NF     80000      // factors
#define NE     160000     // directed edges per direction
#define SDIM   64         // state dim
#define HMDIM  128        // hidden (message MLP)
#define HRDIM  128        // hidden (readout)
#define KIN    136        // 2*S + 8
#define NSTEPS 5

static_assert(NE % 64 == 0, "edge grid exact");

typedef __attribute__((ext_vector_type(8))) short short8;   // 8 bf16 = 4 VGPRs
typedef __attribute__((ext_vector_type(4))) float f32x4;    // MFMA C/D

// ---------- helpers ----------
static __device__ __forceinline__ float bf2f(unsigned short u) {
    return __uint_as_float(((unsigned int)u) << 16);
}
static __device__ __forceinline__ unsigned short f2bf(float f) {
    unsigned int u = __float_as_uint(f);
    u += 0x7fffu + ((u >> 16) & 1u);          // round-to-nearest-even
    return (unsigned short)(u >> 16);
}
static __device__ __forceinline__ float sigm(float x) {
    x = fminf(fmaxf(x, -30.f), 30.f);
    return 1.f / (1.f + __expf(-x));
}
static __device__ __forceinline__ float tanh_f(float x) {
    x = fminf(fmaxf(x, -15.f), 15.f);
    float t = __expf(2.f * x);
    return (t - 1.f) / (t + 1.f);
}
// split f32 -> bf16 hi + bf16 lo (x ~= hi + lo, ~16 mantissa bits kept)
static __device__ __forceinline__ void split8(const float* x, short8& hi, short8& lo) {
    #pragma unroll
    for (int i = 0; i < 8; ++i) {
        unsigned short h = f2bf(x[i]);
        hi[i] = (short)h;
        lo[i] = (short)f2bf(x[i] - bf2f(h));
    }
}
static __device__ __forceinline__ void f4pair_to8(float4 a, float4 b, float* xv) {
    xv[0]=a.x; xv[1]=a.y; xv[2]=a.z; xv[3]=a.w;
    xv[4]=b.x; xv[5]=b.y; xv[6]=b.z; xv[7]=b.w;
}

__global__ void k_zero(float* __restrict__ p, int n) {
    int i = blockIdx.x * blockDim.x + threadIdx.x;
    int stride = gridDim.x * blockDim.x;
    for (; i < n; i += stride) p[i] = 0.f;
}

// ---------- weight transpose for readout (dst[k][j] = src[j][k]) ----------
#define NTR 2
struct TArgs {
    const float* src[NTR];
    float*       dst[NTR];
    int          R[NTR];
    int          C[NTR];
};
__global__ void k_transpose(TArgs a) {
    const int b = blockIdx.x;
    const float* s = a.src[b];
    float* d = a.dst[b];
    const int R = a.R[b], C = a.C[b], n = R * C;
    for (int i = threadIdx.x; i < n; i += blockDim.x) {
        int r = i / C, c = i % C;
        d[c * R + r] = s[i];
    }
}

// ---------- pack weights into B-fragment streams (hi/lo bf16) ----------
#define NPK 10
struct PArgs {
    const float*    src[NPK];
    unsigned short* hi[NPK];
    unsigned short* lo[NPK];
    int             N[NPK], K[NPK], CK[NPK];
};
__global__ void k_pack(PArgs a) {
    const int b = blockIdx.x;
    const float* s = a.src[b];
    unsigned short* ph = a.hi[b];
    unsigned short* pl = a.lo[b];
    const int N = a.N[b], K = a.K[b], CK = a.CK[b];
    const int NT = N >> 4;
    const int total = NT * CK * 512;
    for (int i = threadIdx.x; i < total; i += blockDim.x) {
        int j    = i & 7;
        int ln   = (i >> 3) & 63;
        int tile = i >> 9;
        int tn   = tile % NT;
        int ck   = tile / NT;
        int k = ck * 32 + ((ln >> 4) * 8) + j;
        int n = tn * 16 + (ln & 15);
        float f = (k < K) ? s[n * K + k] : 0.f;
        unsigned short h = f2bf(f);
        ph[i] = h;
        pl[i] = f2bf(f - bf2f(h));
    }
}

// bias sums for GRU r/z gates: o[j] = bih[j] + bhh[j], j in [0,192)
__global__ void k_bsum(const float* bih0, const float* bhh0, float* o0,
                       const float* bih1, const float* bhh1, float* o1) {
    int i = threadIdx.x;
    if (i < 192) { o0[i] = bih0[i] + bhh0[i]; o1[i] = bih1[i] + bhh1[i]; }
}

// ---------- MFMA edge MLP + atomic scatter (chunk-hoisted B loads) ----------
// Block = 64 edges, 128 threads = 2 waves; wave w owns edges [32w,32w+32) as
// two 16-row M-tiles. KEY CHANGE vs rounds 13-18 (all pinned ~100us): per
// K-chunk, ALL 16 B-fragments are loaded into a register block BEFORE any
// MFMA (13 latency windows/wave instead of ~88 serialized load->mfma pairs
// — the invariant stall across R13/14/16/18 was load-use spacing).
__global__ __launch_bounds__(128, 2)
void k_edge_mfma(const float* __restrict__ hrow, const float* __restrict__ hcol,
                 const int* __restrict__ rows, const int* __restrict__ cols,
                 const float* __restrict__ feat,
                 const unsigned short* __restrict__ w1h, const unsigned short* __restrict__ w1l,
                 const unsigned short* __restrict__ w2h, const unsigned short* __restrict__ w2l,
                 const unsigned short* __restrict__ w3h, const unsigned short* __restrict__ w3l,
                 const float* __restrict__ b1, const float* __restrict__ b2,
                 const float* __restrict__ b3,
                 float* __restrict__ nm)
{
    __shared__ unsigned short Hhi[64][136];   // stride 272B: conflict-light
    __shared__ unsigned short Hlo[64][136];   // 34 KB total
    const int lane = threadIdx.x & 63;
    const int wv   = threadIdx.x >> 6;        // 0..1
    const int quad = lane >> 4;               // 0..3
    const int col  = lane & 15;
    int r[2], c[2];
    {
        int e0 = blockIdx.x * 64 + wv * 32 + col;
        r[0] = rows[e0];      c[0] = cols[e0];
        r[1] = rows[e0 + 16]; c[1] = cols[e0 + 16];
    }

    // hoisted gathers: 20 float4 loads issued together
    float4 gR[2][4], gC[2][4], gFr[2], gFc[2];
    #pragma unroll
    for (int mt = 0; mt < 2; ++mt) {
        const float4* pr = (const float4*)(hrow + (size_t)r[mt] * 64);
        const float4* pc = (const float4*)(hcol + (size_t)c[mt] * 64);
        gR[mt][0] = pr[quad * 2];     gR[mt][1] = pr[quad * 2 + 1];
        gR[mt][2] = pr[8 + quad * 2]; gR[mt][3] = pr[8 + quad * 2 + 1];
        gC[mt][0] = pc[quad * 2];     gC[mt][1] = pc[quad * 2 + 1];
        gC[mt][2] = pc[8 + quad * 2]; gC[mt][3] = pc[8 + quad * 2 + 1];
        gFr[mt] = *(const float4*)(feat + (size_t)r[mt] * 4);
        gFc[mt] = *(const float4*)(feat + (size_t)c[mt] * 4);
    }

    f32x4 acc[2][8];
    #pragma unroll
    for (int mt = 0; mt < 2; ++mt)
        #pragma unroll
        for (int t = 0; t < 8; ++t) acc[mt][t] = (f32x4){0.f, 0.f, 0.f, 0.f};

    // ---- layer 1: K = 136 padded to 160 (5 chunks of 32) ----
    #pragma unroll
    for (int ck = 0; ck < 5; ++ck) {
        // B prefetch: whole chunk (16 wide loads back-to-back)
        short8 Bh[8], Bl[8];
        {
            const unsigned short* bh = w1h + (size_t)(ck * 8) * 512 + lane * 8;
            const unsigned short* bl = w1l + (size_t)(ck * 8) * 512 + lane * 8;
            #pragma unroll
            for (int tn = 0; tn < 8; ++tn) {
                Bh[tn] = *(const short8*)(bh + tn * 512);
                Bl[tn] = *(const short8*)(bl + tn * 512);
            }
        }
        // A split (VALU overlaps in-flight loads)
        short8 ahi[2], alo[2];
        #pragma unroll
        for (int mt = 0; mt < 2; ++mt) {
            float xv[8];
            if (ck < 2)      f4pair_to8(gR[mt][ck * 2], gR[mt][ck * 2 + 1], xv);
            else if (ck < 4) f4pair_to8(gC[mt][(ck - 2) * 2], gC[mt][(ck - 2) * 2 + 1], xv);
            else if (quad == 0) f4pair_to8(gFr[mt], gFc[mt], xv);
            else {
                for (int i = 0; i < 8; ++i) xv[i] = 0.f;
            }
            split8(xv, ahi[mt], alo[mt]);
        }
        #pragma unroll
        for (int tn = 0; tn < 8; ++tn) {
            #pragma unroll
            for (int mt = 0; mt < 2; ++mt) {
                acc[mt][tn] = __builtin_amdgcn_mfma_f32_16x16x32_bf16(ahi[mt], Bh[tn], acc[mt][tn], 0, 0, 0);
                acc[mt][tn] = __builtin_amdgcn_mfma_f32_16x16x32_bf16(ahi[mt], Bl[tn], acc[mt][tn], 0, 0, 0);
                acc[mt][tn] = __builtin_amdgcn_mfma_f32_16x16x32_bf16(alo[mt], Bh[tn], acc[mt][tn], 0, 0, 0);
            }
        }
    }
    // epilogue 1: bias + relu -> H (bf16 hi/lo), wave-private rows
    #pragma unroll
    for (int mt = 0; mt < 2; ++mt)
        #pragma unroll
        for (int tn = 0; tn < 8; ++tn) {
            float bias = b1[tn * 16 + col];
            #pragma unroll
            for (int rr = 0; rr < 4; ++rr) {
                float v = fmaxf(acc[mt][tn][rr] + bias, 0.f);
                int m = wv * 32 + mt * 16 + quad * 4 + rr;
                unsigned short h = f2bf(v);
                Hhi[m][tn * 16 + col] = h;
                Hlo[m][tn * 16 + col] = f2bf(v - bf2f(h));
            }
        }

    // ---- layer 2: K = 128 (4 chunks) ----
    #pragma unroll
    for (int mt = 0; mt < 2; ++mt)
        #pragma unroll
        for (int t = 0; t < 8; ++t) acc[mt][t] = (f32x4){0.f, 0.f, 0.f, 0.f};
    {
        const int m0 = wv * 32 + col;
        #pragma unroll
        for (int ck = 0; ck < 4; ++ck) {
            short8 Bh[8], Bl[8];
            {
                const unsigned short* bh = w2h + (size_t)(ck * 8) * 512 + lane * 8;
                const unsigned short* bl = w2l + (size_t)(ck * 8) * 512 + lane * 8;
                #pragma unroll
                for (int tn = 0; tn < 8; ++tn) {
                    Bh[tn] = *(const short8*)(bh + tn * 512);
                    Bl[tn] = *(const short8*)(bl + tn * 512);
                }
            }
            short8 ahi[2], alo[2];
            #pragma unroll
            for (int mt = 0; mt < 2; ++mt) {
                ahi[mt] = *(const short8*)(&Hhi[m0 + mt * 16][ck * 32 + quad * 8]);
                alo[mt] = *(const short8*)(&Hlo[m0 + mt * 16][ck * 32 + quad * 8]);
            }
            #pragma unroll
            for (int tn = 0; tn < 8; ++tn) {
                #pragma unroll
                for (int mt = 0; mt < 2; ++mt) {
                    acc[mt][tn] = __builtin_amdgcn_mfma_f32_16x16x32_bf16(ahi[mt], Bh[tn], acc[mt][tn], 0, 0, 0);
                    acc[mt][tn] = __builtin_amdgcn_mfma_f32_16x16x32_bf16(ahi[mt], Bl[tn], acc[mt][tn], 0, 0, 0);
                    acc[mt][tn] = __builtin_amdgcn_mfma_f32_16x16x32_bf16(alo[mt], Bh[tn], acc[mt][tn], 0, 0, 0);
                }
            }
        }
    }
    // epilogue 2
    #pragma unroll
    for (int mt = 0; mt < 2; ++mt)
        #pragma unroll
        for (int tn = 0; tn < 8; ++tn) {
            float bias = b2[tn * 16 + col];
            #pragma unroll
            for (int rr = 0; rr < 4; ++rr) {
                float v = fmaxf(acc[mt][tn][rr] + bias, 0.f);
                int m = wv * 32 + mt * 16 + quad * 4 + rr;
                unsigned short h = f2bf(v);
                Hhi[m][tn * 16 + col] = h;
                Hlo[m][tn * 16 + col] = f2bf(v - bf2f(h));
            }
        }

    // ---- layer 3: N = 64 (4 tiles), K = 128 ----
    f32x4 a3[2][4];
    #pragma unroll
    for (int mt = 0; mt < 2; ++mt)
        #pragma unroll
        for (int t = 0; t < 4; ++t) a3[mt][t] = (f32x4){0.f, 0.f, 0.f, 0.f};
    {
        const int m0 = wv * 32 + col;
        #pragma unroll
        for (int ck = 0; ck < 4; ++ck) {
            short8 Bh[4], Bl[4];
            {
                const unsigned short* bh = w3h + (size_t)(ck * 4) * 512 + lane * 8;
                const unsigned short* bl = w3l + (size_t)(ck * 4) * 512 + lane * 8;
                #pragma unroll
                for (int tn = 0; tn < 4; ++tn) {
                    Bh[tn] = *(const short8*)(bh + tn * 512);
                    Bl[tn] = *(const short8*)(bl + tn * 512);
                }
            }
            short8 ahi[2], alo[2];
            #pragma unroll
            for (int mt = 0; mt < 2; ++mt) {
                ahi[mt] = *(const short8*)(&Hhi[m0 + mt * 16][ck * 32 + quad * 8]);
                alo[mt] = *(const short8*)(&Hlo[m0 + mt * 16][ck * 32 + quad * 8]);
            }
            #pragma unroll
            for (int tn = 0; tn < 4; ++tn) {
                #pragma unroll
                for (int mt = 0; mt < 2; ++mt) {
                    a3[mt][tn] = __builtin_amdgcn_mfma_f32_16x16x32_bf16(ahi[mt], Bh[tn], a3[mt][tn], 0, 0, 0);
                    a3[mt][tn] = __builtin_amdgcn_mfma_f32_16x16x32_bf16(ahi[mt], Bl[tn], a3[mt][tn], 0, 0, 0);
                    a3[mt][tn] = __builtin_amdgcn_mfma_f32_16x16x32_bf16(alo[mt], Bh[tn], a3[mt][tn], 0, 0, 0);
                }
            }
        }
    }
    // epilogue 3: bias + atomic scatter into nm[cols[edge]]
    #pragma unroll
    for (int mt = 0; mt < 2; ++mt) {
        int cc[4];
        #pragma unroll
        for (int rr = 0; rr < 4; ++rr)
            cc[rr] = cols[blockIdx.x * 64 + wv * 32 + mt * 16 + quad * 4 + rr];
        #pragma unroll
        for (int tn = 0; tn < 4; ++tn) {
            float bias = b3[tn * 16 + col];
            #pragma unroll
            for (int rr = 0; rr < 4; ++rr)
                atomicAdd(&nm[(size_t)cc[rr] * 64 + tn * 16 + col], a3[mt][tn][rr] + bias);
        }
    }
}

// ---------- MFMA GRU: h = GRU(nm, h) (unchanged from round 16) ----------
__global__ __launch_bounds__(128, 2)
void k_gru_mfma(float* __restrict__ nm,
                const unsigned short* __restrict__ wih_h, const unsigned short* __restrict__ wih_l,
                const unsigned short* __restrict__ whh_h, const unsigned short* __restrict__ whh_l,
                const float* __restrict__ bsum,          // bih+bhh [192]
                const float* __restrict__ bih, const float* __restrict__ bhh,
                float* __restrict__ hst, int count)
{
    __shared__ float Hs[64][68];              // 17.4 KB, stride-68 conflict-free
    const int lane = threadIdx.x & 63;
    const int wv   = threadIdx.x >> 6;        // 0..1
    const int quad = lane >> 4;
    const int col  = lane & 15;
    const int base = blockIdx.x * 64;

    float4 am[2][4], ah[2][4];
    #pragma unroll
    for (int mt = 0; mt < 2; ++mt) {
        int ra = base + wv * 32 + mt * 16 + col;
        ra = ra < count ? ra : count - 1;
        const float4* pm = (const float4*)(nm + (size_t)ra * 64);
        const float4* ph = (const float4*)(hst + (size_t)ra * 64);
        am[mt][0] = pm[quad * 2];     am[mt][1] = pm[quad * 2 + 1];
        am[mt][2] = pm[8 + quad * 2]; am[mt][3] = pm[8 + quad * 2 + 1];
        ah[mt][0] = ph[quad * 2];     ah[mt][1] = ph[quad * 2 + 1];
        ah[mt][2] = ph[8 + quad * 2]; ah[mt][3] = ph[8 + quad * 2 + 1];
    }
    #pragma unroll
    for (int mt = 0; mt < 2; ++mt) {
        int rowl = wv * 32 + mt * 16 + col;
        *(float4*)(&Hs[rowl][quad * 8])          = ah[mt][0];
        *(float4*)(&Hs[rowl][quad * 8 + 4])      = ah[mt][1];
        *(float4*)(&Hs[rowl][32 + quad * 8])     = ah[mt][2];
        *(float4*)(&Hs[rowl][32 + quad * 8 + 4]) = ah[mt][3];
    }

    f32x4 rz[2][8], ni[2][4], nh[2][4];
    #pragma unroll
    for (int mt = 0; mt < 2; ++mt) {
        #pragma unroll
        for (int t = 0; t < 8; ++t) rz[mt][t] = (f32x4){0.f, 0.f, 0.f, 0.f};
        #pragma unroll
        for (int t = 0; t < 4; ++t) {
            ni[mt][t] = (f32x4){0.f, 0.f, 0.f, 0.f};
            nh[mt][t] = (f32x4){0.f, 0.f, 0.f, 0.f};
        }
    }

    #pragma unroll
    for (int ck = 0; ck < 2; ++ck) {
        short8 mhi[2], mlo[2], hhi[2], hlo[2];
        #pragma unroll
        for (int mt = 0; mt < 2; ++mt) {
            float xv[8];
            f4pair_to8(am[mt][ck * 2], am[mt][ck * 2 + 1], xv);
            split8(xv, mhi[mt], mlo[mt]);
            f4pair_to8(ah[mt][ck * 2], ah[mt][ck * 2 + 1], xv);
            split8(xv, hhi[mt], hlo[mt]);
        }
        const unsigned short* ih = wih_h + (size_t)(ck * 12) * 512 + lane * 8;
        const unsigned short* il = wih_l + (size_t)(ck * 12) * 512 + lane * 8;
        const unsigned short* hh = whh_h + (size_t)(ck * 12) * 512 + lane * 8;
        const unsigned short* hl = whh_l + (size_t)(ck * 12) * 512 + lane * 8;
        #pragma unroll
        for (int tn = 0; tn < 8; ++tn) {
            short8 bihh = *(const short8*)(ih + tn * 512);
            short8 bihl = *(const short8*)(il + tn * 512);
            short8 bhhh = *(const short8*)(hh + tn * 512);
            short8 bhhl = *(const short8*)(hl + tn * 512);
            #pragma unroll
            for (int mt = 0; mt < 2; ++mt) {
                rz[mt][tn] = __builtin_amdgcn_mfma_f32_16x16x32_bf16(mhi[mt], bihh, rz[mt][tn], 0, 0, 0);
                rz[mt][tn] = __builtin_amdgcn_mfma_f32_16x16x32_bf16(mhi[mt], bihl, rz[mt][tn], 0, 0, 0);
                rz[mt][tn] = __builtin_amdgcn_mfma_f32_16x16x32_bf16(mlo[mt], bihh, rz[mt][tn], 0, 0, 0);
                rz[mt][tn] = __builtin_amdgcn_mfma_f32_16x16x32_bf16(hhi[mt], bhhh, rz[mt][tn], 0, 0, 0);
                rz[mt][tn] = __builtin_amdgcn_mfma_f32_16x16x32_bf16(hhi[mt], bhhl, rz[mt][tn], 0, 0, 0);
                rz[mt][tn] = __builtin_amdgcn_mfma_f32_16x16x32_bf16(hlo[mt], bhhh, rz[mt][tn], 0, 0, 0);
            }
        }
        #pragma unroll
        for (int tn = 8; tn < 12; ++tn) {
            short8 bihh = *(const short8*)(ih + tn * 512);
            short8 bihl = *(const short8*)(il + tn * 512);
            short8 bhhh = *(const short8*)(hh + tn * 512);
            short8 bhhl = *(const short8*)(hl + tn * 512);
            #pragma unroll
            for (int mt = 0; mt < 2; ++mt) {
                ni[mt][tn - 8] = __builtin_amdgcn_mfma_f32_16x16x32_bf16(mhi[mt], bihh, ni[mt][tn - 8], 0, 0, 0);
                ni[mt][tn - 8] = __builtin_amdgcn_mfma_f32_16x16x32_bf16(mhi[mt], bihl, ni[mt][tn - 8], 0, 0, 0);
                ni[mt][tn - 8] = __builtin_amdgcn_mfma_f32_16x16x32_bf16(mlo[mt], bihh, ni[mt][tn - 8], 0, 0, 0);
                nh[mt][tn - 8] = __builtin_amdgcn_mfma_f32_16x16x32_bf16(hhi[mt], bhhh, nh[mt][tn - 8], 0, 0, 0);
                nh[mt][tn - 8] = __builtin_amdgcn_mfma_f32_16x16x32_bf16(hhi[mt], bhhl, nh[mt][tn - 8], 0, 0, 0);
                nh[mt][tn - 8] = __builtin_amdgcn_mfma_f32_16x16x32_bf16(hlo[mt], bhhh, nh[mt][tn - 8], 0, 0, 0);
            }
        }
    }

    #pragma unroll
    for (int mt = 0; mt < 2; ++mt) {
        #pragma unroll
        for (int rr = 0; rr < 4; ++rr) {
            int rowl = wv * 32 + mt * 16 + quad * 4 + rr;
            int grow = base + rowl;
            bool ok = grow < count;
            #pragma unroll
            for (int t = 0; t < 4; ++t) {
                int g = t * 16 + col;
                float rv = sigm(rz[mt][t][rr] + bsum[g]);
                float zv = sigm(rz[mt][4 + t][rr] + bsum[64 + g]);
                float nv = tanh_f(ni[mt][t][rr] + bih[128 + g]
                                  + rv * (nh[mt][t][rr] + bhh[128 + g]));
                if (ok) {
                    float ho = Hs[rowl][g];
                    hst[(size_t)grow * 64 + g] = (1.f - zv) * nv + zv * ho;
                    nm[(size_t)grow * 64 + g] = 0.f;
                }
            }
        }
    }
}

// ---------- readout (unchanged) ----------
__global__ __launch_bounds__(256, 3)
void k_readout(const float* __restrict__ vh,
               const float* __restrict__ w1t, const float* __restrict__ b1,
               const float* __restrict__ w2t, const float* __restrict__ b2,
               const float* __restrict__ w3, const float* __restrict__ b3,
               float* __restrict__ out)
{
    __shared__ float H[HRDIM][64];
    const int lane = threadIdx.x & 63;
    const int wv   = __builtin_amdgcn_readfirstlane(threadIdx.x >> 6);
    const int n0 = blockIdx.x * 64 + lane;
    const int n  = n0 < NN ? n0 : NN - 1;
    const float4* px = (const float4*)(vh + (size_t)n * 64);

    const int j1 = 32 * wv;
    float acc[32];
    #pragma unroll
    for (int j = 0; j < 32; ++j) acc[j] = b1[j1 + j];
    #pragma unroll 4
    for (int q = 0; q < 16; ++q) {
        float4 x4 = px[q];
        const float* wa = w1t + (4 * q + 0) * HRDIM + j1;
        const float* wb = w1t + (4 * q + 1) * HRDIM + j1;
        const float* wc = w1t + (4 * q + 2) * HRDIM + j1;
        const float* wd = w1t + (4 * q + 3) * HRDIM + j1;
        #pragma unroll
        for (int j = 0; j < 32; ++j) {
            acc[j] = fmaf(wa[j], x4.x, acc[j]);
            acc[j] = fmaf(wb[j], x4.y, acc[j]);
            acc[j] = fmaf(wc[j], x4.z, acc[j]);
            acc[j] = fmaf(wd[j], x4.w, acc[j]);
        }
    }
    #pragma unroll
    for (int j = 0; j < 32; ++j) H[j1 + j][lane] = fmaxf(acc[j], 0.f);
    __syncthreads();

    #pragma unroll
    for (int j = 0; j < 32; ++j) acc[j] = b2[j1 + j];
    #pragma unroll 4
    for (int k = 0; k < HRDIM; ++k) {
        float xk = H[k][lane];
        const float* wr = w2t + k * HRDIM + j1;
        #pragma unroll
        for (int j = 0; j < 32; ++j)
            acc[j] = fmaf(wr[j], xk, acc[j]);
    }
    __syncthreads();
    #pragma unroll
    for (int j = 0; j < 32; ++j) H[j1 + j][lane] = fmaxf(acc[j], 0.f);
    __syncthreads();

    if (wv == 0 && n0 < NN) {
        float l0 = b3[0], l1 = b3[1];
        #pragma unroll 8
        for (int k = 0; k < HRDIM; ++k) {
            float hk = H[k][lane];
            l0 = fmaf(w3[k],         hk, l0);
            l1 = fmaf(w3[HRDIM + k], hk, l1);
        }
        float mx = fmaxf(l0, l1);
        float e0 = __expf(l0 - mx), e1 = __expf(l1 - mx);
        float inv = 1.f / (e0 + e1);
        out[2 * n + 0] = e0 * inv;
        out[2 * n + 1] = e1 * inv;
    }
}

// ---------- host ----------
extern "C" void kernel_launch(void* const* d_in, const int* in_sizes, int n_in,
                              void* d_out, int out_size, void* d_ws, size_t ws_size,
                              hipStream_t stream)
{
    // ws (f32 units): states 10,880,000 | ro_t 24,576 | bsum 384 | packed 139,264
    // total 11,044,224 f32 = 44.18 MB
    float* var_h = (float*)d_ws;
    float* fac_h = var_h + 640000;
    float* nm    = fac_h + 5120000;
    float* ro_t  = nm + 5120000;            // 24,576 f32
    float* bsum  = ro_t + 24576;            // 384 f32 (2 x 192)
    unsigned short* pk = (unsigned short*)(bsum + 384); // 278,528 shorts

    const int*   f2v_row  = (const int*)d_in[0];
    const int*   f2v_col  = (const int*)d_in[1];
    const int*   v2f_row  = (const int*)d_in[2];
    const int*   v2f_col  = (const int*)d_in[3];
    const float* f2v_feat = (const float*)d_in[4];
    const float* v2f_feat = (const float*)d_in[5];
    const float* W[26];
    for (int j = 0; j < 26; ++j) W[j] = (const float*)d_in[6 + j];
    // W: 0..5 f2v MLP, 6..11 v2f MLP, 12..15 gf GRU, 16..19 gv GRU, 20..25 readout

    TArgs ta;
    float* T[NTR];
    {
        const float* src[NTR] = { W[20], W[22] };
        int R[NTR] = { HRDIM, HRDIM };
        int C[NTR] = { SDIM, HRDIM };
        size_t off = 0;
        for (int t = 0; t < NTR; ++t) {
            ta.src[t] = src[t]; ta.R[t] = R[t]; ta.C[t] = C[t];
            T[t] = ro_t + off; ta.dst[t] = T[t];
            off += (size_t)R[t] * C[t];
        }
    }
    unsigned short* P[12];
    unsigned short* G[8];
    {
        size_t off = 0;
        int esz[3] = { 20480, 16384, 8192 };
        for (int d = 0; d < 2; ++d)
            for (int m = 0; m < 3; ++m) {
                P[d * 6 + m * 2 + 0] = pk + off; off += esz[m];
                P[d * 6 + m * 2 + 1] = pk + off; off += esz[m];
            }
        for (int t = 0; t < 8; ++t) { G[t] = pk + off; off += 12288; }
    }
    PArgs pa;
    {
        const float* src[NPK] = { W[0], W[2], W[4], W[6], W[8], W[10],
                                  W[12], W[13], W[16], W[17] };
        int N[NPK]  = { HMDIM, HMDIM, SDIM,  HMDIM, HMDIM, SDIM,  192, 192, 192, 192 };
        int K[NPK]  = { KIN,   HMDIM, HMDIM, KIN,   HMDIM, HMDIM, SDIM, SDIM, SDIM, SDIM };
        int CK[NPK] = { 5,     4,     4,     5,     4,     4,     2,   2,   2,   2 };
        unsigned short* hi[NPK] = { P[0], P[2], P[4], P[6], P[8], P[10],
                                    G[0], G[2], G[4], G[6] };
        unsigned short* lo[NPK] = { P[1], P[3], P[5], P[7], P[9], P[11],
                                    G[1], G[3], G[5], G[7] };
        for (int t = 0; t < NPK; ++t) {
            pa.src[t] = src[t]; pa.N[t] = N[t]; pa.K[t] = K[t]; pa.CK[t] = CK[t];
            pa.hi[t] = hi[t];   pa.lo[t] = lo[t];
        }
    }
    k_transpose<<<NTR, 256, 0, stream>>>(ta);
    k_pack<<<NPK, 256, 0, stream>>>(pa);
    k_bsum<<<1, 256, 0, stream>>>(W[14], W[15], bsum, W[18], W[19], bsum + 192);
    k_zero<<<512, 256, 0, stream>>>(var_h, 640000 + 5120000 + 5120000);

    for (int s = 0; s < NSTEPS; ++s) {
        // fac -> var messages into nm[node]; var GRU (gf weights)
        k_edge_mfma<<<NE / 64, 128, 0, stream>>>(
            fac_h, var_h, f2v_row, f2v_col, f2v_feat,
            P[0], P[1], P[2], P[3], P[4], P[5],
            W[1], W[3], W[5], nm);
        k_gru_mfma<<<(NN + 63) / 64, 128, 0, stream>>>(
            nm, G[0], G[1], G[2], G[3], bsum, W[14], W[15], var_h, NN);
        // var -> fac messages into nm[factor]; fac GRU (gv weights)
        k_edge_mfma<<<NE / 64, 128, 0, stream>>>(
            var_h, fac_h, v2f_row, v2f_col, v2f_feat,
            P[6], P[7], P[8], P[9], P[10], P[11],
            W[7], W[9], W[11], nm);
        k_gru_mfma<<<(NF + 63) / 64, 128, 0, stream>>>(
            nm, G[4], G[5], G[6], G[7], bsum + 192, W[18], W[19], fac_h, NF);
    }
    k_readout<<<(NN + 63) / 64, 256, 0, stream>>>(
        var_h, T[0], W[21], T[1], W[23], W[24], W[25],
        (float*)d_out);
}

// Round 20
// 1350.170 us; speedup vs baseline: 1.1890x; 1.0568x over previous
//
#include <hip/hip_runtime.h>

// Problem constants (fixed by reference setup)
#define NN     10000      // variable nodes
#define NF     80000      // factors
#define NE     160000     // directed edges per direction
#define SDIM   64         // state dim
#define HMDIM  128        // hidden (message MLP)
#define HRDIM  128        // hidden (readout)
#define KIN    136        // 2*S + 8
#define NSTEPS 5

static_assert(NE % 64 == 0, "edge grid exact");

typedef __attribute__((ext_vector_type(8))) short short8;   // 8 bf16 = 4 VGPRs
typedef __attribute__((ext_vector_type(4))) float f32x4;    // MFMA C/D

// ---------- helpers ----------
static __device__ __forceinline__ float bf2f(unsigned short u) {
    return __uint_as_float(((unsigned int)u) << 16);
}
static __device__ __forceinline__ unsigned short f2bf(float f) {
    unsigned int u = __float_as_uint(f);
    u += 0x7fffu + ((u >> 16) & 1u);          // round-to-nearest-even
    return (unsigned short)(u >> 16);
}
static __device__ __forceinline__ float sigm(float x) {
    x = fminf(fmaxf(x, -30.f), 30.f);
    return 1.f / (1.f + __expf(-x));
}
static __device__ __forceinline__ float tanh_f(float x) {
    x = fminf(fmaxf(x, -15.f), 15.f);
    float t = __expf(2.f * x);
    return (t - 1.f) / (t + 1.f);
}
// split f32 -> bf16 hi + bf16 lo (x ~= hi + lo, ~16 mantissa bits kept)
static __device__ __forceinline__ void split8(const float* x, short8& hi, short8& lo) {
    #pragma unroll
    for (int i = 0; i < 8; ++i) {
        unsigned short h = f2bf(x[i]);
        hi[i] = (short)h;
        lo[i] = (short)f2bf(x[i] - bf2f(h));
    }
}
static __device__ __forceinline__ void f4pair_to8(float4 a, float4 b, float* xv) {
    xv[0]=a.x; xv[1]=a.y; xv[2]=a.z; xv[3]=a.w;
    xv[4]=b.x; xv[5]=b.y; xv[6]=b.z; xv[7]=b.w;
}

__global__ void k_zero(float* __restrict__ p, int n) {
    int i = blockIdx.x * blockDim.x + threadIdx.x;
    int stride = gridDim.x * blockDim.x;
    for (; i < n; i += stride) p[i] = 0.f;
}

// ---------- weight transpose for readout (dst[k][j] = src[j][k]) ----------
#define NTR 2
struct TArgs {
    const float* src[NTR];
    float*       dst[NTR];
    int          R[NTR];
    int          C[NTR];
};
__global__ void k_transpose(TArgs a) {
    const int b = blockIdx.x;
    const float* s = a.src[b];
    float* d = a.dst[b];
    const int R = a.R[b], C = a.C[b], n = R * C;
    for (int i = threadIdx.x; i < n; i += blockDim.x) {
        int r = i / C, c = i % C;
        d[c * R + r] = s[i];
    }
}

// ---------- pack weights into B-fragment streams (hi/lo bf16) ----------
#define NPK 10
struct PArgs {
    const float*    src[NPK];
    unsigned short* hi[NPK];
    unsigned short* lo[NPK];
    int             N[NPK], K[NPK], CK[NPK];
};
__global__ void k_pack(PArgs a) {
    const int b = blockIdx.x;
    const float* s = a.src[b];
    unsigned short* ph = a.hi[b];
    unsigned short* pl = a.lo[b];
    const int N = a.N[b], K = a.K[b], CK = a.CK[b];
    const int NT = N >> 4;
    const int total = NT * CK * 512;
    for (int i = threadIdx.x; i < total; i += blockDim.x) {
        int j    = i & 7;
        int ln   = (i >> 3) & 63;
        int tile = i >> 9;
        int tn   = tile % NT;
        int ck   = tile / NT;
        int k = ck * 32 + ((ln >> 4) * 8) + j;
        int n = tn * 16 + (ln & 15);
        float f = (k < K) ? s[n * K + k] : 0.f;
        unsigned short h = f2bf(f);
        ph[i] = h;
        pl[i] = f2bf(f - bf2f(h));
    }
}

// bias sums for GRU r/z gates: o[j] = bih[j] + bhh[j], j in [0,192)
__global__ void k_bsum(const float* bih0, const float* bhh0, float* o0,
                       const float* bih1, const float* bhh1, float* o1) {
    int i = threadIdx.x;
    if (i < 192) { o0[i] = bih0[i] + bhh0[i]; o1[i] = bih1[i] + bhh1[i]; }
}

// ---------- MFMA edge MLP + atomic scatter (LDS-staged B fragments) ----------
// Block = 64 edges, 128 threads = 2 waves; wave w owns edges [32w,32w+32) as
// two 16-row M-tiles. KEY CHANGE vs R13-R19 (all pinned 100-120us): per
// K-chunk, B-fragments are staged global->LDS by a COOPERATIVE coalesced
// copy (one latency window per chunk, 13 total, shared by both waves —
// R19's register hoist was defeated by the compiler, VGPR stayed 88), and
// MFMAs feed from ds_read_b128 with fine-grained lgkmcnt scheduling.
__global__ __launch_bounds__(128, 2)
void k_edge_mfma(const float* __restrict__ hrow, const float* __restrict__ hcol,
                 const int* __restrict__ rows, const int* __restrict__ cols,
                 const float* __restrict__ feat,
                 const unsigned short* __restrict__ w1h, const unsigned short* __restrict__ w1l,
                 const unsigned short* __restrict__ w2h, const unsigned short* __restrict__ w2l,
                 const unsigned short* __restrict__ w3h, const unsigned short* __restrict__ w3l,
                 const float* __restrict__ b1, const float* __restrict__ b2,
                 const float* __restrict__ b3,
                 float* __restrict__ nm)
{
    __shared__ unsigned short Hhi[64][136];   // 17.0 KB, stride 272B
    __shared__ unsigned short Hlo[64][136];   // 17.0 KB
    __shared__ unsigned short BldsH[4096];    // 8 KB: one chunk of B hi
    __shared__ unsigned short BldsL[4096];    // 8 KB: one chunk of B lo
    const int tid  = threadIdx.x;
    const int lane = tid & 63;
    const int wv   = tid >> 6;                // 0..1
    const int quad = lane >> 4;               // 0..3
    const int col  = lane & 15;
    int r[2], c[2];
    {
        int e0 = blockIdx.x * 64 + wv * 32 + col;
        r[0] = rows[e0];      c[0] = cols[e0];
        r[1] = rows[e0 + 16]; c[1] = cols[e0 + 16];
    }

    // hoisted gathers: 20 float4 loads issued together
    float4 gR[2][4], gC[2][4], gFr[2], gFc[2];
    #pragma unroll
    for (int mt = 0; mt < 2; ++mt) {
        const float4* pr = (const float4*)(hrow + (size_t)r[mt] * 64);
        const float4* pc = (const float4*)(hcol + (size_t)c[mt] * 64);
        gR[mt][0] = pr[quad * 2];     gR[mt][1] = pr[quad * 2 + 1];
        gR[mt][2] = pr[8 + quad * 2]; gR[mt][3] = pr[8 + quad * 2 + 1];
        gC[mt][0] = pc[quad * 2];     gC[mt][1] = pc[quad * 2 + 1];
        gC[mt][2] = pc[8 + quad * 2]; gC[mt][3] = pc[8 + quad * 2 + 1];
        gFr[mt] = *(const float4*)(feat + (size_t)r[mt] * 4);
        gFc[mt] = *(const float4*)(feat + (size_t)c[mt] * 4);
    }

    f32x4 acc[2][8];
    #pragma unroll
    for (int mt = 0; mt < 2; ++mt)
        #pragma unroll
        for (int t = 0; t < 8; ++t) acc[mt][t] = (f32x4){0.f, 0.f, 0.f, 0.f};

    // ---- layer 1: K = 136 padded to 160 (5 chunks of 32) ----
    #pragma unroll
    for (int ck = 0; ck < 5; ++ck) {
        // cooperative stage: 512 x 16B units (hi) + 512 (lo), coalesced
        {
            const uint4* gh = (const uint4*)(w1h + (size_t)(ck * 8) * 512);
            const uint4* gl = (const uint4*)(w1l + (size_t)(ck * 8) * 512);
            #pragma unroll
            for (int i = 0; i < 4; ++i) {
                ((uint4*)BldsH)[tid + i * 128] = gh[tid + i * 128];
                ((uint4*)BldsL)[tid + i * 128] = gl[tid + i * 128];
            }
        }
        // A split while stage loads are in flight
        short8 ahi[2], alo[2];
        #pragma unroll
        for (int mt = 0; mt < 2; ++mt) {
            float xv[8];
            if (ck < 2)      f4pair_to8(gR[mt][ck * 2], gR[mt][ck * 2 + 1], xv);
            else if (ck < 4) f4pair_to8(gC[mt][(ck - 2) * 2], gC[mt][(ck - 2) * 2 + 1], xv);
            else if (quad == 0) f4pair_to8(gFr[mt], gFc[mt], xv);
            else {
                for (int i = 0; i < 8; ++i) xv[i] = 0.f;
            }
            split8(xv, ahi[mt], alo[mt]);
        }
        __syncthreads();                      // B chunk visible
        #pragma unroll
        for (int tn = 0; tn < 8; ++tn) {
            short8 bhi = *(const short8*)(&BldsH[tn * 512 + lane * 8]);
            short8 blo = *(const short8*)(&BldsL[tn * 512 + lane * 8]);
            #pragma unroll
            for (int mt = 0; mt < 2; ++mt) {
                acc[mt][tn] = __builtin_amdgcn_mfma_f32_16x16x32_bf16(ahi[mt], bhi, acc[mt][tn], 0, 0, 0);
                acc[mt][tn] = __builtin_amdgcn_mfma_f32_16x16x32_bf16(ahi[mt], blo, acc[mt][tn], 0, 0, 0);
                acc[mt][tn] = __builtin_amdgcn_mfma_f32_16x16x32_bf16(alo[mt], bhi, acc[mt][tn], 0, 0, 0);
            }
        }
        __syncthreads();                      // all B reads done before restage
    }
    // epilogue 1: bias + relu -> H (bf16 hi/lo), wave-private rows
    #pragma unroll
    for (int mt = 0; mt < 2; ++mt)
        #pragma unroll
        for (int tn = 0; tn < 8; ++tn) {
            float bias = b1[tn * 16 + col];
            #pragma unroll
            for (int rr = 0; rr < 4; ++rr) {
                float v = fmaxf(acc[mt][tn][rr] + bias, 0.f);
                int m = wv * 32 + mt * 16 + quad * 4 + rr;
                unsigned short h = f2bf(v);
                Hhi[m][tn * 16 + col] = h;
                Hlo[m][tn * 16 + col] = f2bf(v - bf2f(h));
            }
        }

    // ---- layer 2: K = 128 (4 chunks) ----
    #pragma unroll
    for (int mt = 0; mt < 2; ++mt)
        #pragma unroll
        for (int t = 0; t < 8; ++t) acc[mt][t] = (f32x4){0.f, 0.f, 0.f, 0.f};
    {
        const int m0 = wv * 32 + col;
        #pragma unroll
        for (int ck = 0; ck < 4; ++ck) {
            {
                const uint4* gh = (const uint4*)(w2h + (size_t)(ck * 8) * 512);
                const uint4* gl = (const uint4*)(w2l + (size_t)(ck * 8) * 512);
                #pragma unroll
                for (int i = 0; i < 4; ++i) {
                    ((uint4*)BldsH)[tid + i * 128] = gh[tid + i * 128];
                    ((uint4*)BldsL)[tid + i * 128] = gl[tid + i * 128];
                }
            }
            short8 ahi[2], alo[2];
            #pragma unroll
            for (int mt = 0; mt < 2; ++mt) {
                ahi[mt] = *(const short8*)(&Hhi[m0 + mt * 16][ck * 32 + quad * 8]);
                alo[mt] = *(const short8*)(&Hlo[m0 + mt * 16][ck * 32 + quad * 8]);
            }
            __syncthreads();
            #pragma unroll
            for (int tn = 0; tn < 8; ++tn) {
                short8 bhi = *(const short8*)(&BldsH[tn * 512 + lane * 8]);
                short8 blo = *(const short8*)(&BldsL[tn * 512 + lane * 8]);
                #pragma unroll
                for (int mt = 0; mt < 2; ++mt) {
                    acc[mt][tn] = __builtin_amdgcn_mfma_f32_16x16x32_bf16(ahi[mt], bhi, acc[mt][tn], 0, 0, 0);
                    acc[mt][tn] = __builtin_amdgcn_mfma_f32_16x16x32_bf16(ahi[mt], blo, acc[mt][tn], 0, 0, 0);
                    acc[mt][tn] = __builtin_amdgcn_mfma_f32_16x16x32_bf16(alo[mt], bhi, acc[mt][tn], 0, 0, 0);
                }
            }
            __syncthreads();
        }
    }
    // epilogue 2
    #pragma unroll
    for (int mt = 0; mt < 2; ++mt)
        #pragma unroll
        for (int tn = 0; tn < 8; ++tn) {
            float bias = b2[tn * 16 + col];
            #pragma unroll
            for (int rr = 0; rr < 4; ++rr) {
                float v = fmaxf(acc[mt][tn][rr] + bias, 0.f);
                int m = wv * 32 + mt * 16 + quad * 4 + rr;
                unsigned short h = f2bf(v);
                Hhi[m][tn * 16 + col] = h;
                Hlo[m][tn * 16 + col] = f2bf(v - bf2f(h));
            }
        }
    __syncthreads();   // H writes settled before layer-3 stage can race

    // ---- layer 3: N = 64 (4 tiles), K = 128 ----
    f32x4 a3[2][4];
    #pragma unroll
    for (int mt = 0; mt < 2; ++mt)
        #pragma unroll
        for (int t = 0; t < 4; ++t) a3[mt][t] = (f32x4){0.f, 0.f, 0.f, 0.f};
    {
        const int m0 = wv * 32 + col;
        #pragma unroll
        for (int ck = 0; ck < 4; ++ck) {
            {
                const uint4* gh = (const uint4*)(w3h + (size_t)(ck * 4) * 512);
                const uint4* gl = (const uint4*)(w3l + (size_t)(ck * 4) * 512);
                #pragma unroll
                for (int i = 0; i < 2; ++i) {
                    ((uint4*)BldsH)[tid + i * 128] = gh[tid + i * 128];
                    ((uint4*)BldsL)[tid + i * 128] = gl[tid + i * 128];
                }
            }
            short8 ahi[2], alo[2];
            #pragma unroll
            for (int mt = 0; mt < 2; ++mt) {
                ahi[mt] = *(const short8*)(&Hhi[m0 + mt * 16][ck * 32 + quad * 8]);
                alo[mt] = *(const short8*)(&Hlo[m0 + mt * 16][ck * 32 + quad * 8]);
            }
            __syncthreads();
            #pragma unroll
            for (int tn = 0; tn < 4; ++tn) {
                short8 bhi = *(const short8*)(&BldsH[tn * 512 + lane * 8]);
                short8 blo = *(const short8*)(&BldsL[tn * 512 + lane * 8]);
                #pragma unroll
                for (int mt = 0; mt < 2; ++mt) {
                    a3[mt][tn] = __builtin_amdgcn_mfma_f32_16x16x32_bf16(ahi[mt], bhi, a3[mt][tn], 0, 0, 0);
                    a3[mt][tn] = __builtin_amdgcn_mfma_f32_16x16x32_bf16(ahi[mt], blo, a3[mt][tn], 0, 0, 0);
                    a3[mt][tn] = __builtin_amdgcn_mfma_f32_16x16x32_bf16(alo[mt], bhi, a3[mt][tn], 0, 0, 0);
                }
            }
            __syncthreads();
        }
    }
    // epilogue 3: bias + atomic scatter into nm[cols[edge]]
    #pragma unroll
    for (int mt = 0; mt < 2; ++mt) {
        int cc[4];
        #pragma unroll
        for (int rr = 0; rr < 4; ++rr)
            cc[rr] = cols[blockIdx.x * 64 + wv * 32 + mt * 16 + quad * 4 + rr];
        #pragma unroll
        for (int tn = 0; tn < 4; ++tn) {
            float bias = b3[tn * 16 + col];
            #pragma unroll
            for (int rr = 0; rr < 4; ++rr)
                atomicAdd(&nm[(size_t)cc[rr] * 64 + tn * 16 + col], a3[mt][tn][rr] + bias);
        }
    }
}

// ---------- MFMA GRU: h = GRU(nm, h) (unchanged from round 16) ----------
__global__ __launch_bounds__(128, 2)
void k_gru_mfma(float* __restrict__ nm,
                const unsigned short* __restrict__ wih_h, const unsigned short* __restrict__ wih_l,
                const unsigned short* __restrict__ whh_h, const unsigned short* __restrict__ whh_l,
                const float* __restrict__ bsum,          // bih+bhh [192]
                const float* __restrict__ bih, const float* __restrict__ bhh,
                float* __restrict__ hst, int count)
{
    __shared__ float Hs[64][68];              // 17.4 KB, stride-68 conflict-free
    const int lane = threadIdx.x & 63;
    const int wv   = threadIdx.x >> 6;        // 0..1
    const int quad = lane >> 4;
    const int col  = lane & 15;
    const int base = blockIdx.x * 64;

    float4 am[2][4], ah[2][4];
    #pragma unroll
    for (int mt = 0; mt < 2; ++mt) {
        int ra = base + wv * 32 + mt * 16 + col;
        ra = ra < count ? ra : count - 1;
        const float4* pm = (const float4*)(nm + (size_t)ra * 64);
        const float4* ph = (const float4*)(hst + (size_t)ra * 64);
        am[mt][0] = pm[quad * 2];     am[mt][1] = pm[quad * 2 + 1];
        am[mt][2] = pm[8 + quad * 2]; am[mt][3] = pm[8 + quad * 2 + 1];
        ah[mt][0] = ph[quad * 2];     ah[mt][1] = ph[quad * 2 + 1];
        ah[mt][2] = ph[8 + quad * 2]; ah[mt][3] = ph[8 + quad * 2 + 1];
    }
    #pragma unroll
    for (int mt = 0; mt < 2; ++mt) {
        int rowl = wv * 32 + mt * 16 + col;
        *(float4*)(&Hs[rowl][quad * 8])          = ah[mt][0];
        *(float4*)(&Hs[rowl][quad * 8 + 4])      = ah[mt][1];
        *(float4*)(&Hs[rowl][32 + quad * 8])     = ah[mt][2];
        *(float4*)(&Hs[rowl][32 + quad * 8 + 4]) = ah[mt][3];
    }

    f32x4 rz[2][8], ni[2][4], nh[2][4];
    #pragma unroll
    for (int mt = 0; mt < 2; ++mt) {
        #pragma unroll
        for (int t = 0; t < 8; ++t) rz[mt][t] = (f32x4){0.f, 0.f, 0.f, 0.f};
        #pragma unroll
        for (int t = 0; t < 4; ++t) {
            ni[mt][t] = (f32x4){0.f, 0.f, 0.f, 0.f};
            nh[mt][t] = (f32x4){0.f, 0.f, 0.f, 0.f};
        }
    }

    #pragma unroll
    for (int ck = 0; ck < 2; ++ck) {
        short8 mhi[2], mlo[2], hhi[2], hlo[2];
        #pragma unroll
        for (int mt = 0; mt < 2; ++mt) {
            float xv[8];
            f4pair_to8(am[mt][ck * 2], am[mt][ck * 2 + 1], xv);
            split8(xv, mhi[mt], mlo[mt]);
            f4pair_to8(ah[mt][ck * 2], ah[mt][ck * 2 + 1], xv);
            split8(xv, hhi[mt], hlo[mt]);
        }
        const unsigned short* ih = wih_h + (size_t)(ck * 12) * 512 + lane * 8;
        const unsigned short* il = wih_l + (size_t)(ck * 12) * 512 + lane * 8;
        const unsigned short* hh = whh_h + (size_t)(ck * 12) * 512 + lane * 8;
        const unsigned short* hl = whh_l + (size_t)(ck * 12) * 512 + lane * 8;
        #pragma unroll
        for (int tn = 0; tn < 8; ++tn) {
            short8 bihh = *(const short8*)(ih + tn * 512);
            short8 bihl = *(const short8*)(il + tn * 512);
            short8 bhhh = *(const short8*)(hh + tn * 512);
            short8 bhhl = *(const short8*)(hl + tn * 512);
            #pragma unroll
            for (int mt = 0; mt < 2; ++mt) {
                rz[mt][tn] = __builtin_amdgcn_mfma_f32_16x16x32_bf16(mhi[mt], bihh, rz[mt][tn], 0, 0, 0);
                rz[mt][tn] = __builtin_amdgcn_mfma_f32_16x16x32_bf16(mhi[mt], bihl, rz[mt][tn], 0, 0, 0);
                rz[mt][tn] = __builtin_amdgcn_mfma_f32_16x16x32_bf16(mlo[mt], bihh, rz[mt][tn], 0, 0, 0);
                rz[mt][tn] = __builtin_amdgcn_mfma_f32_16x16x32_bf16(hhi[mt], bhhh, rz[mt][tn], 0, 0, 0);
                rz[mt][tn] = __builtin_amdgcn_mfma_f32_16x16x32_bf16(hhi[mt], bhhl, rz[mt][tn], 0, 0, 0);
                rz[mt][tn] = __builtin_amdgcn_mfma_f32_16x16x32_bf16(hlo[mt], bhhh, rz[mt][tn], 0, 0, 0);
            }
        }
        #pragma unroll
        for (int tn = 8; tn < 12; ++tn) {
            short8 bihh = *(const short8*)(ih + tn * 512);
            short8 bihl = *(const short8*)(il + tn * 512);
            short8 bhhh = *(const short8*)(hh + tn * 512);
            short8 bhhl = *(const short8*)(hl + tn * 512);
            #pragma unroll
            for (int mt = 0; mt < 2; ++mt) {
                ni[mt][tn - 8] = __builtin_amdgcn_mfma_f32_16x16x32_bf16(mhi[mt], bihh, ni[mt][tn - 8], 0, 0, 0);
                ni[mt][tn - 8] = __builtin_amdgcn_mfma_f32_16x16x32_bf16(mhi[mt], bihl, ni[mt][tn - 8], 0, 0, 0);
                ni[mt][tn - 8] = __builtin_amdgcn_mfma_f32_16x16x32_bf16(mlo[mt], bihh, ni[mt][tn - 8], 0, 0, 0);
                nh[mt][tn - 8] = __builtin_amdgcn_mfma_f32_16x16x32_bf16(hhi[mt], bhhh, nh[mt][tn - 8], 0, 0, 0);
                nh[mt][tn - 8] = __builtin_amdgcn_mfma_f32_16x16x32_bf16(hhi[mt], bhhl, nh[mt][tn - 8], 0, 0, 0);
                nh[mt][tn - 8] = __builtin_amdgcn_mfma_f32_16x16x32_bf16(hlo[mt], bhhh, nh[mt][tn - 8], 0, 0, 0);
            }
        }
    }

    #pragma unroll
    for (int mt = 0; mt < 2; ++mt) {
        #pragma unroll
        for (int rr = 0; rr < 4; ++rr) {
            int rowl = wv * 32 + mt * 16 + quad * 4 + rr;
            int grow = base + rowl;
            bool ok = grow < count;
            #pragma unroll
            for (int t = 0; t < 4; ++t) {
                int g = t * 16 + col;
                float rv = sigm(rz[mt][t][rr] + bsum[g]);
                float zv = sigm(rz[mt][4 + t][rr] + bsum[64 + g]);
                float nv = tanh_f(ni[mt][t][rr] + bih[128 + g]
                                  + rv * (nh[mt][t][rr] + bhh[128 + g]));
                if (ok) {
                    float ho = Hs[rowl][g];
                    hst[(size_t)grow * 64 + g] = (1.f - zv) * nv + zv * ho;
                    nm[(size_t)grow * 64 + g] = 0.f;
                }
            }
        }
    }
}

// ---------- readout (unchanged) ----------
__global__ __launch_bounds__(256, 3)
void k_readout(const float* __restrict__ vh,
               const float* __restrict__ w1t, const float* __restrict__ b1,
               const float* __restrict__ w2t, const float* __restrict__ b2,
               const float* __restrict__ w3, const float* __restrict__ b3,
               float* __restrict__ out)
{
    __shared__ float H[HRDIM][64];
    const int lane = threadIdx.x & 63;
    const int wv   = __builtin_amdgcn_readfirstlane(threadIdx.x >> 6);
    const int n0 = blockIdx.x * 64 + lane;
    const int n  = n0 < NN ? n0 : NN - 1;
    const float4* px = (const float4*)(vh + (size_t)n * 64);

    const int j1 = 32 * wv;
    float acc[32];
    #pragma unroll
    for (int j = 0; j < 32; ++j) acc[j] = b1[j1 + j];
    #pragma unroll 4
    for (int q = 0; q < 16; ++q) {
        float4 x4 = px[q];
        const float* wa = w1t + (4 * q + 0) * HRDIM + j1;
        const float* wb = w1t + (4 * q + 1) * HRDIM + j1;
        const float* wc = w1t + (4 * q + 2) * HRDIM + j1;
        const float* wd = w1t + (4 * q + 3) * HRDIM + j1;
        #pragma unroll
        for (int j = 0; j < 32; ++j) {
            acc[j] = fmaf(wa[j], x4.x, acc[j]);
            acc[j] = fmaf(wb[j], x4.y, acc[j]);
            acc[j] = fmaf(wc[j], x4.z, acc[j]);
            acc[j] = fmaf(wd[j], x4.w, acc[j]);
        }
    }
    #pragma unroll
    for (int j = 0; j < 32; ++j) H[j1 + j][lane] = fmaxf(acc[j], 0.f);
    __syncthreads();

    #pragma unroll
    for (int j = 0; j < 32; ++j) acc[j] = b2[j1 + j];
    #pragma unroll 4
    for (int k = 0; k < HRDIM; ++k) {
        float xk = H[k][lane];
        const float* wr = w2t + k * HRDIM + j1;
        #pragma unroll
        for (int j = 0; j < 32; ++j)
            acc[j] = fmaf(wr[j], xk, acc[j]);
    }
    __syncthreads();
    #pragma unroll
    for (int j = 0; j < 32; ++j) H[j1 + j][lane] = fmaxf(acc[j], 0.f);
    __syncthreads();

    if (wv == 0 && n0 < NN) {
        float l0 = b3[0], l1 = b3[1];
        #pragma unroll 8
        for (int k = 0; k < HRDIM; ++k) {
            float hk = H[k][lane];
            l0 = fmaf(w3[k],         hk, l0);
            l1 = fmaf(w3[HRDIM + k], hk, l1);
        }
        float mx = fmaxf(l0, l1);
        float e0 = __expf(l0 - mx), e1 = __expf(l1 - mx);
        float inv = 1.f / (e0 + e1);
        out[2 * n + 0] = e0 * inv;
        out[2 * n + 1] = e1 * inv;
    }
}

// ---------- host ----------
extern "C" void kernel_launch(void* const* d_in, const int* in_sizes, int n_in,
                              void* d_out, int out_size, void* d_ws, size_t ws_size,
                              hipStream_t stream)
{
    // ws (f32 units): states 10,880,000 | ro_t 24,576 | bsum 384 | packed 139,264
    // total 11,044,224 f32 = 44.18 MB
    float* var_h = (float*)d_ws;
    float* fac_h = var_h + 640000;
    float* nm    = fac_h + 5120000;
    float* ro_t  = nm + 5120000;            // 24,576 f32
    float* bsum  = ro_t + 24576;            // 384 f32 (2 x 192)
    unsigned short* pk = (unsigned short*)(bsum + 384); // 278,528 shorts

    const int*   f2v_row  = (const int*)d_in[0];
    const int*   f2v_col  = (const int*)d_in[1];
    const int*   v2f_row  = (const int*)d_in[2];
    const int*   v2f_col  = (const int*)d_in[3];
    const float* f2v_feat = (const float*)d_in[4];
    const float* v2f_feat = (const float*)d_in[5];
    const float* W[26];
    for (int j = 0; j < 26; ++j) W[j] = (const float*)d_in[6 + j];
    // W: 0..5 f2v MLP, 6..11 v2f MLP, 12..15 gf GRU, 16..19 gv GRU, 20..25 readout

    TArgs ta;
    float* T[NTR];
    {
        const float* src[NTR] = { W[20], W[22] };
        int R[NTR] = { HRDIM, HRDIM };
        int C[NTR] = { SDIM, HRDIM };
        size_t off = 0;
        for (int t = 0; t < NTR; ++t) {
            ta.src[t] = src[t]; ta.R[t] = R[t]; ta.C[t] = C[t];
            T[t] = ro_t + off; ta.dst[t] = T[t];
            off += (size_t)R[t] * C[t];
        }
    }
    unsigned short* P[12];
    unsigned short* G[8];
    {
        size_t off = 0;
        int esz[3] = { 20480, 16384, 8192 };
        for (int d = 0; d < 2; ++d)
            for (int m = 0; m < 3; ++m) {
                P[d * 6 + m * 2 + 0] = pk + off; off += esz[m];
                P[d * 6 + m * 2 + 1] = pk + off; off += esz[m];
            }
        for (int t = 0; t < 8; ++t) { G[t] = pk + off; off += 12288; }
    }
    PArgs pa;
    {
        const float* src[NPK] = { W[0], W[2], W[4], W[6], W[8], W[10],
                                  W[12], W[13], W[16], W[17] };
        int N[NPK]  = { HMDIM, HMDIM, SDIM,  HMDIM, HMDIM, SDIM,  192, 192, 192, 192 };
        int K[NPK]  = { KIN,   HMDIM, HMDIM, KIN,   HMDIM, HMDIM, SDIM, SDIM, SDIM, SDIM };
        int CK[NPK] = { 5,     4,     4,     5,     4,     4,     2,   2,   2,   2 };
        unsigned short* hi[NPK] = { P[0], P[2], P[4], P[6], P[8], P[10],
                                    G[0], G[2], G[4], G[6] };
        unsigned short* lo[NPK] = { P[1], P[3], P[5], P[7], P[9], P[11],
                                    G[1], G[3], G[5], G[7] };
        for (int t = 0; t < NPK; ++t) {
            pa.src[t] = src[t]; pa.N[t] = N[t]; pa.K[t] = K[t]; pa.CK[t] = CK[t];
            pa.hi[t] = hi[t];   pa.lo[t] = lo[t];
        }
    }
    k_transpose<<<NTR, 256, 0, stream>>>(ta);
    k_pack<<<NPK, 256, 0, stream>>>(pa);
    k_bsum<<<1, 256, 0, stream>>>(W[14], W[15], bsum, W[18], W[19], bsum + 192);
    k_zero<<<512, 256, 0, stream>>>(var_h, 640000 + 5120000 + 5120000);

    for (int s = 0; s < NSTEPS; ++s) {
        // fac -> var messages into nm[node]; var GRU (gf weights)
        k_edge_mfma<<<NE / 64, 128, 0, stream>>>(
            fac_h, var_h, f2v_row, f2v_col, f2v_feat,
            P[0], P[1], P[2], P[3], P[4], P[5],
            W[1], W[3], W[5], nm);
        k_gru_mfma<<<(NN + 63) / 64, 128, 0, stream>>>(
            nm, G[0], G[1], G[2], G[3], bsum, W[14], W[15], var_h, NN);
        // var -> fac messages into nm[factor]; fac GRU (gv weights)
        k_edge_mfma<<<NE / 64, 128, 0, stream>>>(
            var_h, fac_h, v2f_row, v2f_col, v2f_feat,
            P[6], P[7], P[8], P[9], P[10], P[11],
            W[7], W[9], W[11], nm);
        k_gru_mfma<<<(NF + 63) / 64, 128, 0, stream>>>(
            nm, G[4], G[5], G[6], G[7], bsum + 192, W[18], W[19], fac_h, NF);
    }
    k_readout<<<(NN + 63) / 64, 256, 0, stream>>>(
        var_h, T[0], W[21], T[1], W[23], W[24], W[25],
        (float*)d_out);
}